// Round 1
// baseline (1445.059 us; speedup 1.0000x reference)
//
#include <hip/hip_runtime.h>
#include <math.h>

// Problem constants (fixed by the reference).
constexpr int N  = 100000;   // nodes
constexpr int E  = 1600000;  // edges
constexpr int NG = 512;      // graphs
constexpr int NF = 64;
constexpr int H1 = 128;
constexpr int H2 = 64;
constexpr int STEPS = 4;

__device__ __forceinline__ float gelu_f(float x) {
    return 0.5f * x * (1.0f + erff(x * 0.70710678118654752f));
}
__device__ __forceinline__ float sigmoid_f(float x) {
    return 1.0f / (1.0f + expf(-x));
}
__device__ __forceinline__ float waveAllSum(float v) {
    #pragma unroll
    for (int m = 32; m; m >>= 1) v += __shfl_xor(v, m);
    return v;
}

// ---------------- CSR build ----------------
__global__ __launch_bounds__(256) void deg_kernel(const int* __restrict__ ei, int* __restrict__ cnt) {
    int e = blockIdx.x * 256 + threadIdx.x;
    if (e < E) atomicAdd(&cnt[ei[E + e]], 1);  // dst = ei[1][e]
}

// single-block hierarchical exclusive scan of cnt[0..n) -> indptr & cursor (in-place over cnt)
__global__ __launch_bounds__(1024) void scan_kernel(int* __restrict__ cnt, int* __restrict__ indptr, int n) {
    __shared__ int wtot[17];
    int tid = threadIdx.x, lane = tid & 63, w = tid >> 6;
    int running = 0;
    int nch = (n + 1023) / 1024;
    for (int c = 0; c < nch; ++c) {
        int idx = c * 1024 + tid;
        int v = (idx < n) ? cnt[idx] : 0;
        int incl = v;
        #pragma unroll
        for (int off = 1; off < 64; off <<= 1) {
            int t = __shfl_up(incl, off);
            if (lane >= off) incl += t;
        }
        if (lane == 63) wtot[w] = incl;
        __syncthreads();
        if (tid == 0) {
            int a = 0;
            for (int i = 0; i < 16; ++i) { int t = wtot[i]; wtot[i] = a; a += t; }
            wtot[16] = a;
        }
        __syncthreads();
        int excl = running + wtot[w] + incl - v;
        if (idx < n) { indptr[idx] = excl; cnt[idx] = excl; }
        running += wtot[16];
        __syncthreads();
    }
    if (tid == 0) { indptr[n] = running; cnt[n] = running; }
}

__global__ __launch_bounds__(256) void fill_kernel(const int* __restrict__ ei,
                                                   int* __restrict__ cursor,
                                                   int* __restrict__ srcs) {
    int e = blockIdx.x * 256 + threadIdx.x;
    if (e < E) {
        int d = ei[E + e];
        int pos = atomicAdd(&cursor[d], 1);
        srcs[pos] = ei[e];
    }
}

// ---------------- graph ranges (batch is sorted) ----------------
__global__ __launch_bounds__(256) void gstart_init_kernel(int* __restrict__ gstart) {
    int i = blockIdx.x * 256 + threadIdx.x;
    if (i <= NG) gstart[i] = N;
}
__global__ __launch_bounds__(256) void gstart_scatter_kernel(const int* __restrict__ batch, int* __restrict__ gstart) {
    int n = blockIdx.x * 256 + threadIdx.x;
    if (n < N) atomicMin(&gstart[batch[n]], n);
}
__global__ __launch_bounds__(64) void gstart_fix_kernel(int* __restrict__ gstart) {
    if (threadIdx.x == 0) {
        for (int g = NG - 1; g >= 0; --g)
            gstart[g] = min(gstart[g], gstart[g + 1]);
    }
}

// ---------------- tiled fp32 linear: out = act(in @ W.T + b) ----------------
// TN=64 nodes per block, full OD per block, K chunked by 64. 8 nodes x OPT outs per thread.
template <int ID, int OD, bool GELU>
__global__ __launch_bounds__(256) void lin_kernel(const float* __restrict__ in,
                                                  const float* __restrict__ W,
                                                  const float* __restrict__ bias,
                                                  float* __restrict__ out, int nrows) {
    constexpr int KC = 64;
    constexpr int NCH = ID / KC;
    constexpr int TN = 64;
    constexpr int NPT = 8;
    constexpr int OPT = (TN * OD) / (256 * NPT);  // 128->4, 64->2
    constexpr int LS = KC + 2;                    // pad: conflict-free float2 reads
    __shared__ __align__(16) float xs[TN * LS];
    __shared__ __align__(16) float Wl[OD * LS];
    int tid = threadIdx.x;
    int nb = blockIdx.x * TN;
    int ng = tid & 7;    // node = ng + 8*i
    int og = tid >> 3;   // o = og*OPT + j
    float acc[NPT][OPT];
    #pragma unroll
    for (int i = 0; i < NPT; ++i)
        #pragma unroll
        for (int j = 0; j < OPT; ++j) acc[i][j] = 0.f;

    for (int c = 0; c < NCH; ++c) {
        int kb = c * KC;
        for (int i = tid; i < TN * KC; i += 256) {
            int nn = i / KC, f = i % KC;
            int row = nb + nn;
            xs[nn * LS + f] = (row < nrows) ? in[row * ID + kb + f] : 0.f;
        }
        for (int i = tid; i < OD * KC; i += 256) {
            int o = i / KC, f = i % KC;
            Wl[o * LS + f] = W[o * ID + kb + f];
        }
        __syncthreads();
        for (int f = 0; f < KC; f += 2) {
            float2 xv[NPT], wv[OPT];
            #pragma unroll
            for (int i = 0; i < NPT; ++i) xv[i] = *(const float2*)&xs[(ng + 8 * i) * LS + f];
            #pragma unroll
            for (int j = 0; j < OPT; ++j) wv[j] = *(const float2*)&Wl[(og * OPT + j) * LS + f];
            #pragma unroll
            for (int i = 0; i < NPT; ++i)
                #pragma unroll
                for (int j = 0; j < OPT; ++j) {
                    acc[i][j] += xv[i].x * wv[j].x;
                    acc[i][j] += xv[i].y * wv[j].y;
                }
        }
        __syncthreads();
    }
    #pragma unroll
    for (int i = 0; i < NPT; ++i) {
        int row = nb + ng + 8 * i;
        if (row < nrows) {
            #pragma unroll
            for (int j = 0; j < OPT; ++j) {
                int o = og * OPT + j;
                float v = acc[i][j] + bias[o];
                if (GELU) v = gelu_f(v);
                out[row * OD + o] = v;
            }
        }
    }
}

// ---------------- GIN aggregation: out[n] = h[n] + sum_{src in N(n)} h[src]  (H1=128 feats) ----
__global__ __launch_bounds__(256) void agg_kernel(const float* __restrict__ h,
                                                  const int* __restrict__ indptr,
                                                  const int* __restrict__ srcs,
                                                  float* __restrict__ out) {
    int wave = threadIdx.x >> 6, lane = threadIdx.x & 63;
    int n = blockIdx.x * 4 + wave;
    if (n >= N) return;
    const float2* h2 = (const float2*)h;  // 64 float2 per row
    float2 acc = h2[(size_t)n * 64 + lane];
    int s0 = indptr[n], s1 = indptr[n + 1];
    int deg = s1 - s0;
    int pre = (lane < deg) ? srcs[s0 + lane] : 0;
    int m1 = deg < 64 ? deg : 64;
    for (int j = 0; j < m1; ++j) {
        int s = __shfl(pre, j);
        float2 v = h2[(size_t)s * 64 + lane];
        acc.x += v.x; acc.y += v.y;
    }
    for (int j = 64; j < deg; ++j) {
        int s = srcs[s0 + j];
        float2 v = h2[(size_t)s * 64 + lane];
        acc.x += v.x; acc.y += v.y;
    }
    ((float2*)out)[(size_t)n * 64 + lane] = acc;
}

// ---------------- row L2-normalize (64 feats, wave per node) ----------------
__global__ __launch_bounds__(256) void norm_kernel(const float* __restrict__ in, float* __restrict__ out) {
    int wave = threadIdx.x >> 6, lane = threadIdx.x & 63;
    int n = blockIdx.x * 4 + wave;
    if (n >= N) return;
    float v = in[(size_t)n * 64 + lane];
    float ss = waveAllSum(v * v);
    float denom = fmaxf(sqrtf(ss), 1e-12f);
    out[(size_t)n * 64 + lane] = v / denom;
}

// ---------------- Set2Set LSTM (2 cells), one block (64 thr) per graph ----------------
__global__ __launch_bounds__(64) void lstm_kernel(const float* __restrict__ q_star,
                                                  float* __restrict__ h0, float* __restrict__ c0,
                                                  float* __restrict__ h1, float* __restrict__ c1,
                                                  const float* __restrict__ Wih0, const float* __restrict__ Whh0,
                                                  const float* __restrict__ bih0, const float* __restrict__ bhh0,
                                                  const float* __restrict__ Wih1, const float* __restrict__ Whh1,
                                                  const float* __restrict__ bih1, const float* __restrict__ bhh1) {
    int g = blockIdx.x, j = threadIdx.x;
    __shared__ float qs[2 * H2];
    __shared__ float h0v[H2], h1v[H2], xb[H2];
    qs[j] = q_star[g * 2 * H2 + j];
    qs[H2 + j] = q_star[g * 2 * H2 + H2 + j];
    h0v[j] = h0[g * H2 + j];
    h1v[j] = h1[g * H2 + j];
    __syncthreads();

    // cell 0: x = q_star (128), h = h0
    float gate[4];
    #pragma unroll
    for (int r4 = 0; r4 < 4; ++r4) {
        int row = r4 * H2 + j;
        float a = bih0[row] + bhh0[row];
        const float* wi = Wih0 + row * 2 * H2;
        const float* wh = Whh0 + row * H2;
        for (int k = 0; k < 2 * H2; ++k) a += qs[k] * wi[k];
        for (int k = 0; k < H2; ++k) a += h0v[k] * wh[k];
        gate[r4] = a;
    }
    {
        float ii = sigmoid_f(gate[0]), ff = sigmoid_f(gate[1]);
        float gg = tanhf(gate[2]), oo = sigmoid_f(gate[3]);
        float c = ff * c0[g * H2 + j] + ii * gg;
        float h = oo * tanhf(c);
        c0[g * H2 + j] = c; h0[g * H2 + j] = h; xb[j] = h;
    }
    __syncthreads();

    // cell 1: x = new h0 (64), h = h1
    #pragma unroll
    for (int r4 = 0; r4 < 4; ++r4) {
        int row = r4 * H2 + j;
        float a = bih1[row] + bhh1[row];
        const float* wi = Wih1 + row * H2;
        const float* wh = Whh1 + row * H2;
        for (int k = 0; k < H2; ++k) a += xb[k] * wi[k];
        for (int k = 0; k < H2; ++k) a += h1v[k] * wh[k];
        gate[r4] = a;
    }
    {
        float ii = sigmoid_f(gate[0]), ff = sigmoid_f(gate[1]);
        float gg = tanhf(gate[2]), oo = sigmoid_f(gate[3]);
        float c = ff * c1[g * H2 + j] + ii * gg;
        float h = oo * tanhf(c);
        c1[g * H2 + j] = c; h1[g * H2 + j] = h;  // h1 == q
    }
}

// ---------------- Set2Set attention: one block (4 waves) per graph ----------------
__global__ __launch_bounds__(256) void attn_kernel(const float* __restrict__ hn,
                                                   const int* __restrict__ gstart,
                                                   const float* __restrict__ q,      // h1 state
                                                   float* __restrict__ q_star) {
    int g = blockIdx.x;
    __shared__ float ql[H2];
    __shared__ float rp[4][H2];
    __shared__ float sp[4], mp[4];
    int tid = threadIdx.x, w = tid >> 6, lane = tid & 63;
    if (tid < H2) ql[tid] = q[g * H2 + tid];
    __syncthreads();
    int s0 = gstart[g], s1 = gstart[g + 1];
    float qf = ql[lane];

    float lm = -INFINITY;
    for (int n = s0 + w; n < s1; n += 4) {
        float e = waveAllSum(hn[(size_t)n * H2 + lane] * qf);
        lm = fmaxf(lm, e);
    }
    if (lane == 0) mp[w] = lm;
    __syncthreads();
    float m = fmaxf(fmaxf(mp[0], mp[1]), fmaxf(mp[2], mp[3]));

    float ls = 0.f, racc = 0.f;
    for (int n = s0 + w; n < s1; n += 4) {
        float v = hn[(size_t)n * H2 + lane];
        float e = waveAllSum(v * qf);
        float p = expf(e - m);
        ls += p;
        racc += p * v;
    }
    rp[w][lane] = racc;
    if (lane == 0) sp[w] = ls;
    __syncthreads();
    if (tid < H2) {
        float r = rp[0][tid] + rp[1][tid] + rp[2][tid] + rp[3][tid];
        float s = sp[0] + sp[1] + sp[2] + sp[3];
        q_star[g * 2 * H2 + tid] = ql[tid];
        q_star[g * 2 * H2 + H2 + tid] = r / (s + 1e-16f);
    }
}

// ---------------- output head: z = fc2(gelu(fc1(q_star))) ----------------
__global__ __launch_bounds__(256) void fcout_kernel(const float* __restrict__ q_star,
                                                    const float* __restrict__ W1, const float* __restrict__ b1,
                                                    const float* __restrict__ W2, const float* __restrict__ b2,
                                                    float* __restrict__ z) {
    __shared__ float W1l[32 * 128];
    __shared__ float b1l[32], W2l[32];
    int tid = threadIdx.x;
    for (int i = tid; i < 32 * 128; i += 256) W1l[i] = W1[i];
    if (tid < 32) { b1l[tid] = b1[tid]; W2l[tid] = W2[tid]; }
    __syncthreads();
    int g = blockIdx.x * 256 + tid;
    float acc[32];
    #pragma unroll
    for (int j = 0; j < 32; ++j) acc[j] = b1l[j];
    for (int k = 0; k < 128; ++k) {
        float qv = q_star[g * 128 + k];
        #pragma unroll
        for (int j = 0; j < 32; ++j) acc[j] += qv * W1l[j * 128 + k];
    }
    float zv = b2[0];
    #pragma unroll
    for (int j = 0; j < 32; ++j) zv += gelu_f(acc[j]) * W2l[j];
    z[g] = zv;
}

extern "C" void kernel_launch(void* const* d_in, const int* in_sizes, int n_in,
                              void* d_out, int out_size, void* d_ws, size_t ws_size,
                              hipStream_t stream) {
    const float* x       = (const float*)d_in[0];
    const int*   ei      = (const int*)d_in[1];
    const int*   batch   = (const int*)d_in[2];
    const float* nfc_W   = (const float*)d_in[3];
    const float* nfc_b   = (const float*)d_in[4];
    const float* gc1_W   = (const float*)d_in[5];
    const float* gc1_b   = (const float*)d_in[6];
    const float* gc2_W   = (const float*)d_in[7];
    const float* gc2_b   = (const float*)d_in[8];
    const float* l0_Wih  = (const float*)d_in[9];
    const float* l0_Whh  = (const float*)d_in[10];
    const float* l0_bih  = (const float*)d_in[11];
    const float* l0_bhh  = (const float*)d_in[12];
    const float* l1_Wih  = (const float*)d_in[13];
    const float* l1_Whh  = (const float*)d_in[14];
    const float* l1_bih  = (const float*)d_in[15];
    const float* l1_bhh  = (const float*)d_in[16];
    const float* fc1_W   = (const float*)d_in[17];
    const float* fc1_b   = (const float*)d_in[18];
    const float* fc2_W   = (const float*)d_in[19];
    const float* fc2_b   = (const float*)d_in[20];

    float* out = (float*)d_out;          // [0,512): z ; [512, 512+N*64): h
    float* hn_out = out + NG;

    // workspace layout
    char* p = (char*)d_ws;
    auto take = [&](size_t bytes) {
        char* r = p;
        p += (bytes + 255) & ~size_t(255);
        return r;
    };
    float* bufA   = (float*)take((size_t)N * H1 * 4);
    float* bufB   = (float*)take((size_t)N * H1 * 4);
    int*   indptr = (int*)take((size_t)(N + 1) * 4);
    int*   cursor = (int*)take((size_t)(N + 1) * 4);
    int*   srcs   = (int*)take((size_t)E * 4);
    int*   gstart = (int*)take((size_t)(NG + 1) * 4);
    float* h0s    = (float*)take((size_t)NG * H2 * 4);
    float* c0s    = (float*)take((size_t)NG * H2 * 4);
    float* h1s    = (float*)take((size_t)NG * H2 * 4);
    float* c1s    = (float*)take((size_t)NG * H2 * 4);
    float* qstar  = (float*)take((size_t)NG * 2 * H2 * 4);

    // zero the degree/cursor array and LSTM/q_star state (contiguous from h0s)
    hipMemsetAsync(cursor, 0, (size_t)(N + 1) * 4, stream);
    hipMemsetAsync(h0s, 0, (size_t)NG * (4 * H2 + 2 * H2) * 4, stream);

    // CSR build
    deg_kernel<<<(E + 255) / 256, 256, 0, stream>>>(ei, cursor);
    scan_kernel<<<1, 1024, 0, stream>>>(cursor, indptr, N);
    fill_kernel<<<(E + 255) / 256, 256, 0, stream>>>(ei, cursor, srcs);

    // graph ranges
    gstart_init_kernel<<<3, 256, 0, stream>>>(gstart);
    gstart_scatter_kernel<<<(N + 255) / 256, 256, 0, stream>>>(batch, gstart);
    gstart_fix_kernel<<<1, 64, 0, stream>>>(gstart);

    // node feature pipeline
    int linGrid = (N + 63) / 64;
    lin_kernel<NF, H1, true><<<linGrid, 256, 0, stream>>>(x, nfc_W, nfc_b, bufA, N);     // h1
    agg_kernel<<<(N + 3) / 4, 256, 0, stream>>>(bufA, indptr, srcs, bufB);               // s1
    lin_kernel<H1, H1, true><<<linGrid, 256, 0, stream>>>(bufB, gc1_W, gc1_b, bufA, N);  // h2
    agg_kernel<<<(N + 3) / 4, 256, 0, stream>>>(bufA, indptr, srcs, bufB);               // s2
    lin_kernel<H1, H2, true><<<linGrid, 256, 0, stream>>>(bufB, gc2_W, gc2_b, bufA, N);  // h3 [N,64]
    norm_kernel<<<(N + 3) / 4, 256, 0, stream>>>(bufA, hn_out);                          // normalized h -> output

    // Set2Set
    for (int step = 0; step < STEPS; ++step) {
        lstm_kernel<<<NG, 64, 0, stream>>>(qstar, h0s, c0s, h1s, c1s,
                                           l0_Wih, l0_Whh, l0_bih, l0_bhh,
                                           l1_Wih, l1_Whh, l1_bih, l1_bhh);
        attn_kernel<<<NG, 256, 0, stream>>>(hn_out, gstart, h1s, qstar);
    }

    // head
    fcout_kernel<<<2, 256, 0, stream>>>(qstar, fc1_W, fc1_b, fc2_W, fc2_b, out);
}

// Round 2
// 1134.705 us; speedup vs baseline: 1.2735x; 1.2735x over previous
//
#include <hip/hip_runtime.h>
#include <math.h>

// Problem constants (fixed by the reference).
constexpr int N  = 100000;   // nodes
constexpr int E  = 1600000;  // edges
constexpr int NG = 512;      // graphs
constexpr int NF = 64;
constexpr int H1 = 128;
constexpr int H2 = 64;
constexpr int STEPS = 4;

// CSR bucket binning
constexpr int BW   = 256;                 // nodes per bucket (dst >> 8)
constexpr int NB   = (N + BW - 1) / BW;   // 391 buckets
constexpr int CAP  = 4864;                // per-bucket edge capacity (mean 4096 + 12 sigma)
constexpr int CHUNK = 8192;               // edges per bin_scatter block

__device__ __forceinline__ float gelu_f(float x) {
    return 0.5f * x * (1.0f + erff(x * 0.70710678118654752f));
}
__device__ __forceinline__ float sigmoid_f(float x) {
    return 1.0f / (1.0f + expf(-x));
}
__device__ __forceinline__ float waveAllSum(float v) {
    #pragma unroll
    for (int m = 32; m; m >>= 1) v += __shfl_xor(v, m);
    return v;
}

// ---------------- CSR build, phase 0: init bucket cursors ----------------
__global__ __launch_bounds__(256) void bcur_init_kernel(int* __restrict__ bcursor) {
    int b = blockIdx.x * 256 + threadIdx.x;
    if (b < NB) bcursor[b] = b * CAP;
}

// ---------------- CSR build, phase 1: bin edges into bucket-strided (src,dst) pairs ----
__global__ __launch_bounds__(256) void bin_scatter_kernel(const int* __restrict__ ei,
                                                          int* __restrict__ bcursor,
                                                          int2* __restrict__ pairs) {
    __shared__ int hist[NB];
    __shared__ int start_s[NB];
    __shared__ int lcur[NB];
    int tid = threadIdx.x;
    int e0 = blockIdx.x * CHUNK;
    for (int b = tid; b < NB; b += 256) hist[b] = 0;
    __syncthreads();
    // pass 1: local histogram of dst buckets
    #pragma unroll 4
    for (int k = 0; k < CHUNK / 256; ++k) {
        int e = e0 + k * 256 + tid;
        if (e < E) atomicAdd(&hist[ei[E + e] >> 8], 1);
    }
    __syncthreads();
    // reserve contiguous chunks per bucket
    for (int b = tid; b < NB; b += 256) {
        if (hist[b]) start_s[b] = atomicAdd(&bcursor[b], hist[b]);
        lcur[b] = 0;
    }
    __syncthreads();
    // pass 2: scatter pairs
    #pragma unroll 4
    for (int k = 0; k < CHUNK / 256; ++k) {
        int e = e0 + k * 256 + tid;
        if (e < E) {
            int d = ei[E + e];
            int s = ei[e];
            int b = d >> 8;
            int pos = start_s[b] + atomicAdd(&lcur[b], 1);
            if (pos < (b + 1) * CAP) pairs[pos] = make_int2(s, d);
        }
    }
}

// ---------------- CSR build, phase 2: per-bucket local CSR in LDS ----------------
// Emits per-node (start,end) range into nrange, srcs filled per bucket at b*CAP.
__global__ __launch_bounds__(256) void csr_bucket_kernel(const int2* __restrict__ pairs,
                                                         const int* __restrict__ bcursor,
                                                         int* __restrict__ srcs,
                                                         int2* __restrict__ nrange) {
    __shared__ int cnt_l[256];
    __shared__ int cur_l[256];
    __shared__ int wt[4];
    int b = blockIdx.x;
    int tid = threadIdx.x;
    int base = b * CAP;
    int cnt = bcursor[b] - base;
    if (cnt > CAP) cnt = CAP;
    cnt_l[tid] = 0;
    __syncthreads();
    for (int i = tid; i < cnt; i += 256) {
        atomicAdd(&cnt_l[pairs[base + i].y & 255], 1);
    }
    __syncthreads();
    // 256-wide exclusive scan (4 waves)
    int v = cnt_l[tid];
    int lane = tid & 63, w = tid >> 6;
    int incl = v;
    #pragma unroll
    for (int off = 1; off < 64; off <<= 1) {
        int t = __shfl_up(incl, off);
        if (lane >= off) incl += t;
    }
    if (lane == 63) wt[w] = incl;
    __syncthreads();
    int add = 0;
    for (int i = 0; i < w; ++i) add += wt[i];
    int excl = add + incl - v;
    int node = b * 256 + tid;
    if (node < N) {
        nrange[node] = make_int2(base + excl, base + excl + v);
    }
    cur_l[tid] = excl;
    __syncthreads();
    for (int i = tid; i < cnt; i += 256) {
        int2 p = pairs[base + i];
        int d = p.y & 255;
        int pos = atomicAdd(&cur_l[d], 1);
        srcs[base + pos] = p.x;
    }
}

// ---------------- graph ranges via binary search (batch is sorted) ----------------
__global__ __launch_bounds__(256) void gstart_kernel(const int* __restrict__ batch, int* __restrict__ gstart) {
    int g = blockIdx.x * 256 + threadIdx.x;
    if (g > NG) return;
    if (g == NG) { gstart[NG] = N; return; }
    int lo = 0, hi = N;
    while (lo < hi) {
        int mid = (lo + hi) >> 1;
        if (batch[mid] < g) lo = mid + 1; else hi = mid;
    }
    gstart[g] = lo;
}

// ---------------- tiled fp32 linear: out = act(in @ W.T + b) ----------------
// TN=64 nodes per block, full OD per block, K chunked by 64. 8 nodes x OPT outs per thread.
template <int ID, int OD, bool GELU>
__global__ __launch_bounds__(256) void lin_kernel(const float* __restrict__ in,
                                                  const float* __restrict__ W,
                                                  const float* __restrict__ bias,
                                                  float* __restrict__ out, int nrows) {
    constexpr int KC = 64;
    constexpr int NCH = ID / KC;
    constexpr int TN = 64;
    constexpr int NPT = 8;
    constexpr int OPT = (TN * OD) / (256 * NPT);  // 128->4, 64->2
    constexpr int LS = KC + 2;                    // pad: conflict-free float2 reads
    __shared__ __align__(16) float xs[TN * LS];
    __shared__ __align__(16) float Wl[OD * LS];
    int tid = threadIdx.x;
    int nb = blockIdx.x * TN;
    int ng = tid & 7;    // node = ng + 8*i
    int og = tid >> 3;   // o = og*OPT + j
    float acc[NPT][OPT];
    #pragma unroll
    for (int i = 0; i < NPT; ++i)
        #pragma unroll
        for (int j = 0; j < OPT; ++j) acc[i][j] = 0.f;

    for (int c = 0; c < NCH; ++c) {
        int kb = c * KC;
        for (int i = tid; i < TN * KC; i += 256) {
            int nn = i / KC, f = i % KC;
            int row = nb + nn;
            xs[nn * LS + f] = (row < nrows) ? in[row * ID + kb + f] : 0.f;
        }
        for (int i = tid; i < OD * KC; i += 256) {
            int o = i / KC, f = i % KC;
            Wl[o * LS + f] = W[o * ID + kb + f];
        }
        __syncthreads();
        for (int f = 0; f < KC; f += 2) {
            float2 xv[NPT], wv[OPT];
            #pragma unroll
            for (int i = 0; i < NPT; ++i) xv[i] = *(const float2*)&xs[(ng + 8 * i) * LS + f];
            #pragma unroll
            for (int j = 0; j < OPT; ++j) wv[j] = *(const float2*)&Wl[(og * OPT + j) * LS + f];
            #pragma unroll
            for (int i = 0; i < NPT; ++i)
                #pragma unroll
                for (int j = 0; j < OPT; ++j) {
                    acc[i][j] += xv[i].x * wv[j].x;
                    acc[i][j] += xv[i].y * wv[j].y;
                }
        }
        __syncthreads();
    }
    #pragma unroll
    for (int i = 0; i < NPT; ++i) {
        int row = nb + ng + 8 * i;
        if (row < nrows) {
            #pragma unroll
            for (int j = 0; j < OPT; ++j) {
                int o = og * OPT + j;
                float v = acc[i][j] + bias[o];
                if (GELU) v = gelu_f(v);
                out[row * OD + o] = v;
            }
        }
    }
}

// ---------------- GIN aggregation: out[n] = h[n] + sum_{src in N(n)} h[src]  (H1=128 feats) ----
__global__ __launch_bounds__(256) void agg_kernel(const float* __restrict__ h,
                                                  const int2* __restrict__ nrange,
                                                  const int* __restrict__ srcs,
                                                  float* __restrict__ out) {
    int wave = threadIdx.x >> 6, lane = threadIdx.x & 63;
    int n = blockIdx.x * 4 + wave;
    if (n >= N) return;
    const float2* h2 = (const float2*)h;  // 64 float2 per row
    float2 acc = h2[(size_t)n * 64 + lane];
    int2 rng = nrange[n];
    int s0 = rng.x;
    int deg = rng.y - rng.x;
    int pre = (lane < deg) ? srcs[s0 + lane] : 0;
    int m1 = deg < 64 ? deg : 64;
    for (int j = 0; j < m1; ++j) {
        int s = __shfl(pre, j);
        float2 v = h2[(size_t)s * 64 + lane];
        acc.x += v.x; acc.y += v.y;
    }
    for (int j = 64; j < deg; ++j) {
        int s = srcs[s0 + j];
        float2 v = h2[(size_t)s * 64 + lane];
        acc.x += v.x; acc.y += v.y;
    }
    ((float2*)out)[(size_t)n * 64 + lane] = acc;
}

// ---------------- row L2-normalize (64 feats, wave per node) ----------------
__global__ __launch_bounds__(256) void norm_kernel(const float* __restrict__ in, float* __restrict__ out) {
    int wave = threadIdx.x >> 6, lane = threadIdx.x & 63;
    int n = blockIdx.x * 4 + wave;
    if (n >= N) return;
    float v = in[(size_t)n * 64 + lane];
    float ss = waveAllSum(v * v);
    float denom = fmaxf(sqrtf(ss), 1e-12f);
    out[(size_t)n * 64 + lane] = v / denom;
}

// ---------------- Set2Set LSTM (2 cells), one block (64 thr) per graph ----------------
__global__ __launch_bounds__(64) void lstm_kernel(const float* __restrict__ q_star,
                                                  float* __restrict__ h0, float* __restrict__ c0,
                                                  float* __restrict__ h1, float* __restrict__ c1,
                                                  const float* __restrict__ Wih0, const float* __restrict__ Whh0,
                                                  const float* __restrict__ bih0, const float* __restrict__ bhh0,
                                                  const float* __restrict__ Wih1, const float* __restrict__ Whh1,
                                                  const float* __restrict__ bih1, const float* __restrict__ bhh1) {
    int g = blockIdx.x, j = threadIdx.x;
    __shared__ float qs[2 * H2];
    __shared__ float h0v[H2], h1v[H2], xb[H2];
    qs[j] = q_star[g * 2 * H2 + j];
    qs[H2 + j] = q_star[g * 2 * H2 + H2 + j];
    h0v[j] = h0[g * H2 + j];
    h1v[j] = h1[g * H2 + j];
    __syncthreads();

    // cell 0: x = q_star (128), h = h0
    float gate[4];
    #pragma unroll
    for (int r4 = 0; r4 < 4; ++r4) {
        int row = r4 * H2 + j;
        float a = bih0[row] + bhh0[row];
        const float* wi = Wih0 + row * 2 * H2;
        const float* wh = Whh0 + row * H2;
        for (int k = 0; k < 2 * H2; ++k) a += qs[k] * wi[k];
        for (int k = 0; k < H2; ++k) a += h0v[k] * wh[k];
        gate[r4] = a;
    }
    {
        float ii = sigmoid_f(gate[0]), ff = sigmoid_f(gate[1]);
        float gg = tanhf(gate[2]), oo = sigmoid_f(gate[3]);
        float c = ff * c0[g * H2 + j] + ii * gg;
        float h = oo * tanhf(c);
        c0[g * H2 + j] = c; h0[g * H2 + j] = h; xb[j] = h;
    }
    __syncthreads();

    // cell 1: x = new h0 (64), h = h1
    #pragma unroll
    for (int r4 = 0; r4 < 4; ++r4) {
        int row = r4 * H2 + j;
        float a = bih1[row] + bhh1[row];
        const float* wi = Wih1 + row * H2;
        const float* wh = Whh1 + row * H2;
        for (int k = 0; k < H2; ++k) a += xb[k] * wi[k];
        for (int k = 0; k < H2; ++k) a += h1v[k] * wh[k];
        gate[r4] = a;
    }
    {
        float ii = sigmoid_f(gate[0]), ff = sigmoid_f(gate[1]);
        float gg = tanhf(gate[2]), oo = sigmoid_f(gate[3]);
        float c = ff * c1[g * H2 + j] + ii * gg;
        float h = oo * tanhf(c);
        c1[g * H2 + j] = c; h1[g * H2 + j] = h;  // h1 == q
    }
}

// ---------------- Set2Set attention: one block (4 waves) per graph ----------------
__global__ __launch_bounds__(256) void attn_kernel(const float* __restrict__ hn,
                                                   const int* __restrict__ gstart,
                                                   const float* __restrict__ q,      // h1 state
                                                   float* __restrict__ q_star) {
    int g = blockIdx.x;
    __shared__ float ql[H2];
    __shared__ float rp[4][H2];
    __shared__ float sp[4], mp[4];
    int tid = threadIdx.x, w = tid >> 6, lane = tid & 63;
    if (tid < H2) ql[tid] = q[g * H2 + tid];
    __syncthreads();
    int s0 = gstart[g], s1 = gstart[g + 1];
    float qf = ql[lane];

    float lm = -INFINITY;
    for (int n = s0 + w; n < s1; n += 4) {
        float e = waveAllSum(hn[(size_t)n * H2 + lane] * qf);
        lm = fmaxf(lm, e);
    }
    if (lane == 0) mp[w] = lm;
    __syncthreads();
    float m = fmaxf(fmaxf(mp[0], mp[1]), fmaxf(mp[2], mp[3]));

    float ls = 0.f, racc = 0.f;
    for (int n = s0 + w; n < s1; n += 4) {
        float v = hn[(size_t)n * H2 + lane];
        float e = waveAllSum(v * qf);
        float p = expf(e - m);
        ls += p;
        racc += p * v;
    }
    rp[w][lane] = racc;
    if (lane == 0) sp[w] = ls;
    __syncthreads();
    if (tid < H2) {
        float r = rp[0][tid] + rp[1][tid] + rp[2][tid] + rp[3][tid];
        float s = sp[0] + sp[1] + sp[2] + sp[3];
        q_star[g * 2 * H2 + tid] = ql[tid];
        q_star[g * 2 * H2 + H2 + tid] = r / (s + 1e-16f);
    }
}

// ---------------- output head: z = fc2(gelu(fc1(q_star))) ----------------
__global__ __launch_bounds__(256) void fcout_kernel(const float* __restrict__ q_star,
                                                    const float* __restrict__ W1, const float* __restrict__ b1,
                                                    const float* __restrict__ W2, const float* __restrict__ b2,
                                                    float* __restrict__ z) {
    __shared__ float W1l[32 * 128];
    __shared__ float b1l[32], W2l[32];
    int tid = threadIdx.x;
    for (int i = tid; i < 32 * 128; i += 256) W1l[i] = W1[i];
    if (tid < 32) { b1l[tid] = b1[tid]; W2l[tid] = W2[tid]; }
    __syncthreads();
    int g = blockIdx.x * 256 + tid;
    float acc[32];
    #pragma unroll
    for (int j = 0; j < 32; ++j) acc[j] = b1l[j];
    for (int k = 0; k < 128; ++k) {
        float qv = q_star[g * 128 + k];
        #pragma unroll
        for (int j = 0; j < 32; ++j) acc[j] += qv * W1l[j * 128 + k];
    }
    float zv = b2[0];
    #pragma unroll
    for (int j = 0; j < 32; ++j) zv += gelu_f(acc[j]) * W2l[j];
    z[g] = zv;
}

extern "C" void kernel_launch(void* const* d_in, const int* in_sizes, int n_in,
                              void* d_out, int out_size, void* d_ws, size_t ws_size,
                              hipStream_t stream) {
    const float* x       = (const float*)d_in[0];
    const int*   ei      = (const int*)d_in[1];
    const int*   batch   = (const int*)d_in[2];
    const float* nfc_W   = (const float*)d_in[3];
    const float* nfc_b   = (const float*)d_in[4];
    const float* gc1_W   = (const float*)d_in[5];
    const float* gc1_b   = (const float*)d_in[6];
    const float* gc2_W   = (const float*)d_in[7];
    const float* gc2_b   = (const float*)d_in[8];
    const float* l0_Wih  = (const float*)d_in[9];
    const float* l0_Whh  = (const float*)d_in[10];
    const float* l0_bih  = (const float*)d_in[11];
    const float* l0_bhh  = (const float*)d_in[12];
    const float* l1_Wih  = (const float*)d_in[13];
    const float* l1_Whh  = (const float*)d_in[14];
    const float* l1_bih  = (const float*)d_in[15];
    const float* l1_bhh  = (const float*)d_in[16];
    const float* fc1_W   = (const float*)d_in[17];
    const float* fc1_b   = (const float*)d_in[18];
    const float* fc2_W   = (const float*)d_in[19];
    const float* fc2_b   = (const float*)d_in[20];

    float* out = (float*)d_out;          // [0,512): z ; [512, 512+N*64): h
    float* hn_out = out + NG;

    // workspace layout
    char* p = (char*)d_ws;
    auto take = [&](size_t bytes) {
        char* r = p;
        p += (bytes + 255) & ~size_t(255);
        return r;
    };
    float* bufA   = (float*)take((size_t)N * H1 * 4);   // also aliased as pairs during CSR build
    float* bufB   = (float*)take((size_t)N * H1 * 4);
    int*   srcs   = (int*)take((size_t)NB * CAP * 4);
    int2*  nrange = (int2*)take((size_t)N * 8);
    int*   bcursor= (int*)take((size_t)NB * 4);
    int*   gstart = (int*)take((size_t)(NG + 1) * 4);
    float* h0s    = (float*)take((size_t)NG * H2 * 4);
    float* c0s    = (float*)take((size_t)NG * H2 * 4);
    float* h1s    = (float*)take((size_t)NG * H2 * 4);
    float* c1s    = (float*)take((size_t)NG * H2 * 4);
    float* qstar  = (float*)take((size_t)NG * 2 * H2 * 4);

    int2* pairs = (int2*)bufA;  // NB*CAP*8 = 15.2 MB <= 51.2 MB, free until first lin

    // zero LSTM/q_star state (contiguous from h0s)
    hipMemsetAsync(h0s, 0, (size_t)NG * (4 * H2 + 2 * H2) * 4, stream);

    // CSR build (bucket-binned, no global scan)
    bcur_init_kernel<<<(NB + 255) / 256, 256, 0, stream>>>(bcursor);
    bin_scatter_kernel<<<(E + CHUNK - 1) / CHUNK, 256, 0, stream>>>(ei, bcursor, pairs);
    csr_bucket_kernel<<<NB, 256, 0, stream>>>(pairs, bcursor, srcs, nrange);

    // graph ranges (binary search over sorted batch)
    gstart_kernel<<<3, 256, 0, stream>>>(batch, gstart);

    // node feature pipeline
    int linGrid = (N + 63) / 64;
    lin_kernel<NF, H1, true><<<linGrid, 256, 0, stream>>>(x, nfc_W, nfc_b, bufA, N);     // h1
    agg_kernel<<<(N + 3) / 4, 256, 0, stream>>>(bufA, nrange, srcs, bufB);               // s1
    lin_kernel<H1, H1, true><<<linGrid, 256, 0, stream>>>(bufB, gc1_W, gc1_b, bufA, N);  // h2
    agg_kernel<<<(N + 3) / 4, 256, 0, stream>>>(bufA, nrange, srcs, bufB);               // s2
    lin_kernel<H1, H2, true><<<linGrid, 256, 0, stream>>>(bufB, gc2_W, gc2_b, bufA, N);  // h3 [N,64]
    norm_kernel<<<(N + 3) / 4, 256, 0, stream>>>(bufA, hn_out);                          // normalized h -> output

    // Set2Set
    for (int step = 0; step < STEPS; ++step) {
        lstm_kernel<<<NG, 64, 0, stream>>>(qstar, h0s, c0s, h1s, c1s,
                                           l0_Wih, l0_Whh, l0_bih, l0_bhh,
                                           l1_Wih, l1_Whh, l1_bih, l1_bhh);
        attn_kernel<<<NG, 256, 0, stream>>>(hn_out, gstart, h1s, qstar);
    }

    // head
    fcout_kernel<<<2, 256, 0, stream>>>(qstar, fc1_W, fc1_b, fc2_W, fc2_b, out);
}

// Round 3
// 786.626 us; speedup vs baseline: 1.8370x; 1.4425x over previous
//
#include <hip/hip_runtime.h>
#include <hip/hip_bf16.h>
#include <math.h>

// Problem constants (fixed by the reference).
constexpr int N  = 100000;   // nodes
constexpr int E  = 1600000;  // edges
constexpr int NG = 512;      // graphs
constexpr int NF = 64;
constexpr int H1 = 128;
constexpr int H2 = 64;

// CSR bucket binning
constexpr int BW   = 256;                 // nodes per bucket (dst >> 8)
constexpr int NB   = (N + BW - 1) / BW;   // 391 buckets
constexpr int CAP  = 4864;                // per-bucket edge capacity (mean 4096 + 12 sigma)
constexpr int CHUNK = 8192;               // edges per bin_scatter block

__device__ __forceinline__ float gelu_f(float x) {
    return 0.5f * x * (1.0f + erff(x * 0.70710678118654752f));
}
__device__ __forceinline__ float sigmoid_f(float x) {
    return 1.0f / (1.0f + expf(-x));
}
__device__ __forceinline__ float waveAllSum(float v) {
    #pragma unroll
    for (int m = 32; m; m >>= 1) v += __shfl_xor(v, m);
    return v;
}
__device__ __forceinline__ unsigned short f2bf(float x) {
    __hip_bfloat16 b = __float2bfloat16(x);
    return *reinterpret_cast<unsigned short*>(&b);
}

// ---------------- CSR build, phase 0: init bucket cursors ----------------
__global__ __launch_bounds__(256) void bcur_init_kernel(int* __restrict__ bcursor) {
    int b = blockIdx.x * 256 + threadIdx.x;
    if (b < NB) bcursor[b] = b * CAP;
}

// ---------------- CSR build, phase 1: bin edges into bucket-strided (src,dst) pairs ----
__global__ __launch_bounds__(256) void bin_scatter_kernel(const int* __restrict__ ei,
                                                          int* __restrict__ bcursor,
                                                          int2* __restrict__ pairs) {
    __shared__ int hist[NB];
    __shared__ int start_s[NB];
    __shared__ int lcur[NB];
    int tid = threadIdx.x;
    int e0 = blockIdx.x * CHUNK;
    for (int b = tid; b < NB; b += 256) hist[b] = 0;
    __syncthreads();
    #pragma unroll 4
    for (int k = 0; k < CHUNK / 256; ++k) {
        int e = e0 + k * 256 + tid;
        if (e < E) atomicAdd(&hist[ei[E + e] >> 8], 1);
    }
    __syncthreads();
    for (int b = tid; b < NB; b += 256) {
        if (hist[b]) start_s[b] = atomicAdd(&bcursor[b], hist[b]);
        lcur[b] = 0;
    }
    __syncthreads();
    #pragma unroll 4
    for (int k = 0; k < CHUNK / 256; ++k) {
        int e = e0 + k * 256 + tid;
        if (e < E) {
            int d = ei[E + e];
            int s = ei[e];
            int b = d >> 8;
            int pos = start_s[b] + atomicAdd(&lcur[b], 1);
            if (pos < (b + 1) * CAP) pairs[pos] = make_int2(s, d);
        }
    }
}

// ---------------- CSR build, phase 2: per-bucket local CSR in LDS ----------------
__global__ __launch_bounds__(256) void csr_bucket_kernel(const int2* __restrict__ pairs,
                                                         const int* __restrict__ bcursor,
                                                         int* __restrict__ srcs,
                                                         int2* __restrict__ nrange) {
    __shared__ int cnt_l[256];
    __shared__ int cur_l[256];
    __shared__ int wt[4];
    int b = blockIdx.x;
    int tid = threadIdx.x;
    int base = b * CAP;
    int cnt = bcursor[b] - base;
    if (cnt > CAP) cnt = CAP;
    cnt_l[tid] = 0;
    __syncthreads();
    for (int i = tid; i < cnt; i += 256) {
        atomicAdd(&cnt_l[pairs[base + i].y & 255], 1);
    }
    __syncthreads();
    int v = cnt_l[tid];
    int lane = tid & 63, w = tid >> 6;
    int incl = v;
    #pragma unroll
    for (int off = 1; off < 64; off <<= 1) {
        int t = __shfl_up(incl, off);
        if (lane >= off) incl += t;
    }
    if (lane == 63) wt[w] = incl;
    __syncthreads();
    int add = 0;
    for (int i = 0; i < w; ++i) add += wt[i];
    int excl = add + incl - v;
    int node = b * 256 + tid;
    if (node < N) {
        nrange[node] = make_int2(base + excl, base + excl + v);
    }
    cur_l[tid] = excl;
    __syncthreads();
    for (int i = tid; i < cnt; i += 256) {
        int2 p = pairs[base + i];
        int d = p.y & 255;
        int pos = atomicAdd(&cur_l[d], 1);
        srcs[base + pos] = p.x;
    }
}

// ---------------- graph ranges via binary search (batch is sorted) ----------------
__global__ __launch_bounds__(256) void gstart_kernel(const int* __restrict__ batch, int* __restrict__ gstart) {
    int g = blockIdx.x * 256 + threadIdx.x;
    if (g > NG) return;
    if (g == NG) { gstart[NG] = N; return; }
    int lo = 0, hi = N;
    while (lo < hi) {
        int mid = (lo + hi) >> 1;
        if (batch[mid] < g) lo = mid + 1; else hi = mid;
    }
    gstart[g] = lo;
}

// ---------------- tiled fp32 linear ----------------
// OUT_MODE: 0 = fp32, 1 = bf16-packed, 2 = fp32 + row-L2-normalize (OD=64 only)
template <int ID, int OD, bool GELU, int OUT_MODE>
__global__ __launch_bounds__(256) void lin_kernel(const float* __restrict__ in,
                                                  const float* __restrict__ W,
                                                  const float* __restrict__ bias,
                                                  void* __restrict__ out_v, int nrows) {
    constexpr int KC = 64;
    constexpr int NCH = ID / KC;
    constexpr int TN = 64;
    constexpr int NPT = 8;
    constexpr int OPT = (TN * OD) / (256 * NPT);  // 128->4, 64->2
    constexpr int LS = KC + 2;
    __shared__ __align__(16) float xs[TN * LS];
    __shared__ __align__(16) float Wl[OD * LS];
    int tid = threadIdx.x;
    int nb = blockIdx.x * TN;
    int ng = tid & 7;
    int og = tid >> 3;
    float acc[NPT][OPT];
    #pragma unroll
    for (int i = 0; i < NPT; ++i)
        #pragma unroll
        for (int j = 0; j < OPT; ++j) acc[i][j] = 0.f;

    for (int c = 0; c < NCH; ++c) {
        int kb = c * KC;
        for (int i = tid; i < TN * KC; i += 256) {
            int nn = i / KC, f = i % KC;
            int row = nb + nn;
            xs[nn * LS + f] = (row < nrows) ? in[row * ID + kb + f] : 0.f;
        }
        for (int i = tid; i < OD * KC; i += 256) {
            int o = i / KC, f = i % KC;
            Wl[o * LS + f] = W[o * ID + kb + f];
        }
        __syncthreads();
        for (int f = 0; f < KC; f += 2) {
            float2 xv[NPT], wv[OPT];
            #pragma unroll
            for (int i = 0; i < NPT; ++i) xv[i] = *(const float2*)&xs[(ng + 8 * i) * LS + f];
            #pragma unroll
            for (int j = 0; j < OPT; ++j) wv[j] = *(const float2*)&Wl[(og * OPT + j) * LS + f];
            #pragma unroll
            for (int i = 0; i < NPT; ++i)
                #pragma unroll
                for (int j = 0; j < OPT; ++j) {
                    acc[i][j] += xv[i].x * wv[j].x;
                    acc[i][j] += xv[i].y * wv[j].y;
                }
        }
        __syncthreads();
    }

    if (OUT_MODE == 2) {
        // stage activations to LDS, then wave-per-row L2 normalize. OD==64.
        float* st = xs;  // reuse as [64][65]
        #pragma unroll
        for (int i = 0; i < NPT; ++i) {
            int rl = ng + 8 * i;
            #pragma unroll
            for (int j = 0; j < OPT; ++j) {
                int o = og * OPT + j;
                float v = acc[i][j] + bias[o];
                if (GELU) v = gelu_f(v);
                st[rl * 65 + o] = ((nb + rl) < nrows) ? v : 0.f;
            }
        }
        __syncthreads();
        float* out = (float*)out_v;
        int w = tid >> 6, lane = tid & 63;
        for (int r = w * 16; r < w * 16 + 16; ++r) {
            int row = nb + r;
            float v = st[r * 65 + lane];
            float ss = waveAllSum(v * v);
            float denom = fmaxf(sqrtf(ss), 1e-12f);
            if (row < nrows) out[(size_t)row * 64 + lane] = v / denom;
        }
        return;
    }

    #pragma unroll
    for (int i = 0; i < NPT; ++i) {
        int row = nb + ng + 8 * i;
        if (row >= nrows) continue;
        float v[OPT];
        #pragma unroll
        for (int j = 0; j < OPT; ++j) {
            int o = og * OPT + j;
            v[j] = acc[i][j] + bias[o];
            if (GELU) v[j] = gelu_f(v[j]);
        }
        if (OUT_MODE == 1) {
            // pack OPT bf16 outputs (OPT=4 for OD=128): two uints
            unsigned int u0 = (unsigned int)f2bf(v[0]) | ((unsigned int)f2bf(v[1]) << 16);
            if (OPT == 4) {
                unsigned int u1 = (unsigned int)f2bf(v[2]) | ((unsigned int)f2bf(v[3]) << 16);
                ((uint2*)out_v)[(size_t)row * (OD / 4) + og] = make_uint2(u0, u1);
            } else {
                ((unsigned int*)out_v)[(size_t)row * (OD / 2) + og] = u0;
            }
        } else {
            float* out = (float*)out_v;
            #pragma unroll
            for (int j = 0; j < OPT; ++j) out[(size_t)row * OD + og * OPT + j] = v[j];
        }
    }
}

// ---------------- GIN aggregation (bf16 table): out[n] = h[n] + sum h[src], H1=128 ----
__global__ __launch_bounds__(256) void agg_kernel(const unsigned int* __restrict__ hb,
                                                  const int2* __restrict__ nrange,
                                                  const int* __restrict__ srcs,
                                                  float* __restrict__ out) {
    int wave = threadIdx.x >> 6, lane = threadIdx.x & 63;
    int n = blockIdx.x * 4 + wave;
    if (n >= N) return;
    unsigned int u = hb[(size_t)n * 64 + lane];
    float accx = __uint_as_float(u << 16);
    float accy = __uint_as_float(u & 0xffff0000u);
    int2 rng = nrange[n];
    int s0 = rng.x;
    int deg = rng.y - rng.x;
    int pre = (lane < deg) ? srcs[s0 + lane] : 0;
    int m1 = deg < 64 ? deg : 64;
    for (int j = 0; j < m1; ++j) {
        int s = __shfl(pre, j);
        unsigned int uv = hb[(size_t)s * 64 + lane];
        accx += __uint_as_float(uv << 16);
        accy += __uint_as_float(uv & 0xffff0000u);
    }
    for (int j = 64; j < deg; ++j) {
        int s = srcs[s0 + j];
        unsigned int uv = hb[(size_t)s * 64 + lane];
        accx += __uint_as_float(uv << 16);
        accy += __uint_as_float(uv & 0xffff0000u);
    }
    ((float2*)out)[(size_t)n * 64 + lane] = make_float2(accx, accy);
}

// ---------------- fused Set2Set: one block per graph, all 4 steps ----------------
__global__ __launch_bounds__(256) void set2set_kernel(const float* __restrict__ hn,
                                                      const int* __restrict__ gstart,
                                                      const float* __restrict__ Wih0, const float* __restrict__ Whh0,
                                                      const float* __restrict__ bih0, const float* __restrict__ bhh0,
                                                      const float* __restrict__ Wih1, const float* __restrict__ Whh1,
                                                      const float* __restrict__ bih1, const float* __restrict__ bhh1,
                                                      float* __restrict__ qstar_out) {
    int g = blockIdx.x;
    int tid = threadIdx.x, w = tid >> 6, lane = tid & 63;
    __shared__ __align__(16) float qs[2 * H2];
    __shared__ __align__(16) float gates[256];
    __shared__ __align__(16) float h0v[H2], c0v[H2], h1v[H2], c1v[H2];
    __shared__ float rp[4][H2];
    __shared__ float sp[4], mp[4];
    if (tid < 2 * H2) qs[tid] = 0.f;
    if (tid < H2) { h0v[tid] = 0.f; c0v[tid] = 0.f; h1v[tid] = 0.f; c1v[tid] = 0.f; }
    int s0 = gstart[g], s1 = gstart[g + 1];
    __syncthreads();

    for (int step = 0; step < 4; ++step) {
        // cell 0: gate row = tid; x = qs (128), h = h0v
        {
            float a = bih0[tid] + bhh0[tid];
            const float4* wi = (const float4*)(Wih0 + tid * 2 * H2);
            const float4* wh = (const float4*)(Whh0 + tid * H2);
            const float4* q4 = (const float4*)qs;
            const float4* h4 = (const float4*)h0v;
            #pragma unroll 8
            for (int k = 0; k < 2 * H2 / 4; ++k) {
                float4 wv = wi[k], xv = q4[k];
                a += wv.x * xv.x + wv.y * xv.y + wv.z * xv.z + wv.w * xv.w;
            }
            #pragma unroll 8
            for (int k = 0; k < H2 / 4; ++k) {
                float4 wv = wh[k], xv = h4[k];
                a += wv.x * xv.x + wv.y * xv.y + wv.z * xv.z + wv.w * xv.w;
            }
            gates[tid] = a;
        }
        __syncthreads();
        if (tid < H2) {
            float ii = sigmoid_f(gates[tid]), ff = sigmoid_f(gates[H2 + tid]);
            float gg = tanhf(gates[2 * H2 + tid]), oo = sigmoid_f(gates[3 * H2 + tid]);
            float c = ff * c0v[tid] + ii * gg;
            float h = oo * tanhf(c);
            c0v[tid] = c; h0v[tid] = h;
        }
        __syncthreads();
        // cell 1: gate row = tid; x = h0v (new), h = h1v
        {
            float a = bih1[tid] + bhh1[tid];
            const float4* wi = (const float4*)(Wih1 + tid * H2);
            const float4* wh = (const float4*)(Whh1 + tid * H2);
            const float4* x4 = (const float4*)h0v;
            const float4* h4 = (const float4*)h1v;
            #pragma unroll 8
            for (int k = 0; k < H2 / 4; ++k) {
                float4 wv = wi[k], xv = x4[k];
                a += wv.x * xv.x + wv.y * xv.y + wv.z * xv.z + wv.w * xv.w;
            }
            #pragma unroll 8
            for (int k = 0; k < H2 / 4; ++k) {
                float4 wv = wh[k], xv = h4[k];
                a += wv.x * xv.x + wv.y * xv.y + wv.z * xv.z + wv.w * xv.w;
            }
            gates[tid] = a;
        }
        __syncthreads();
        if (tid < H2) {
            float ii = sigmoid_f(gates[tid]), ff = sigmoid_f(gates[H2 + tid]);
            float gg = tanhf(gates[2 * H2 + tid]), oo = sigmoid_f(gates[3 * H2 + tid]);
            float c = ff * c1v[tid] + ii * gg;
            float h = oo * tanhf(c);
            c1v[tid] = c; h1v[tid] = h;   // h1v == q
        }
        __syncthreads();
        // attention (online softmax, single pass over this graph's nodes)
        float qf = h1v[lane];
        float m = -INFINITY, s = 0.f, racc = 0.f;
        for (int n = s0 + w; n < s1; n += 4) {
            float v = hn[(size_t)n * H2 + lane];
            float e = waveAllSum(v * qf);
            if (e > m) {
                float sc = expf(m - e);
                s = s * sc + 1.f;
                racc = racc * sc + v;
                m = e;
            } else {
                float p = expf(e - m);
                s += p;
                racc += p * v;
            }
        }
        rp[w][lane] = racc;
        if (lane == 0) { sp[w] = s; mp[w] = m; }
        __syncthreads();
        if (tid < H2) {
            float r = 0.f, st = 0.f;
            if (s1 > s0) {
                float M = fmaxf(fmaxf(mp[0], mp[1]), fmaxf(mp[2], mp[3]));
                #pragma unroll
                for (int ww = 0; ww < 4; ++ww) {
                    float sc = (mp[ww] == -INFINITY) ? 0.f : expf(mp[ww] - M);
                    st += sp[ww] * sc;
                    r += rp[ww][tid] * sc;
                }
                r = r / (st + 1e-16f);
            }
            qs[tid] = h1v[tid];
            qs[H2 + tid] = r;
        }
        __syncthreads();
    }
    if (tid < 2 * H2) qstar_out[g * 2 * H2 + tid] = qs[tid];
}

// ---------------- output head: z = fc2(gelu(fc1(q_star))) ----------------
__global__ __launch_bounds__(256) void fcout_kernel(const float* __restrict__ q_star,
                                                    const float* __restrict__ W1, const float* __restrict__ b1,
                                                    const float* __restrict__ W2, const float* __restrict__ b2,
                                                    float* __restrict__ z) {
    __shared__ float W1l[32 * 128];
    __shared__ float b1l[32], W2l[32];
    int tid = threadIdx.x;
    for (int i = tid; i < 32 * 128; i += 256) W1l[i] = W1[i];
    if (tid < 32) { b1l[tid] = b1[tid]; W2l[tid] = W2[tid]; }
    __syncthreads();
    int g = blockIdx.x * 256 + tid;
    float acc[32];
    #pragma unroll
    for (int j = 0; j < 32; ++j) acc[j] = b1l[j];
    for (int k = 0; k < 128; ++k) {
        float qv = q_star[g * 128 + k];
        #pragma unroll
        for (int j = 0; j < 32; ++j) acc[j] += qv * W1l[j * 128 + k];
    }
    float zv = b2[0];
    #pragma unroll
    for (int j = 0; j < 32; ++j) zv += gelu_f(acc[j]) * W2l[j];
    z[g] = zv;
}

extern "C" void kernel_launch(void* const* d_in, const int* in_sizes, int n_in,
                              void* d_out, int out_size, void* d_ws, size_t ws_size,
                              hipStream_t stream) {
    const float* x       = (const float*)d_in[0];
    const int*   ei      = (const int*)d_in[1];
    const int*   batch   = (const int*)d_in[2];
    const float* nfc_W   = (const float*)d_in[3];
    const float* nfc_b   = (const float*)d_in[4];
    const float* gc1_W   = (const float*)d_in[5];
    const float* gc1_b   = (const float*)d_in[6];
    const float* gc2_W   = (const float*)d_in[7];
    const float* gc2_b   = (const float*)d_in[8];
    const float* l0_Wih  = (const float*)d_in[9];
    const float* l0_Whh  = (const float*)d_in[10];
    const float* l0_bih  = (const float*)d_in[11];
    const float* l0_bhh  = (const float*)d_in[12];
    const float* l1_Wih  = (const float*)d_in[13];
    const float* l1_Whh  = (const float*)d_in[14];
    const float* l1_bih  = (const float*)d_in[15];
    const float* l1_bhh  = (const float*)d_in[16];
    const float* fc1_W   = (const float*)d_in[17];
    const float* fc1_b   = (const float*)d_in[18];
    const float* fc2_W   = (const float*)d_in[19];
    const float* fc2_b   = (const float*)d_in[20];

    float* out = (float*)d_out;          // [0,512): z ; [512, 512+N*64): normalized h
    float* hn_out = out + NG;

    char* p = (char*)d_ws;
    auto take = [&](size_t bytes) {
        char* r = p;
        p += (bytes + 255) & ~size_t(255);
        return r;
    };
    float*        sbuf  = (float*)take((size_t)N * H1 * 4);        // s1 / s2 (fp32); aliased as pairs pre-lin
    unsigned int* hbbuf = (unsigned int*)take((size_t)N * H1 * 2); // h1 / h2 (bf16-packed)
    int*   srcs   = (int*)take((size_t)NB * CAP * 4);
    int2*  nrange = (int2*)take((size_t)N * 8);
    int*   bcursor= (int*)take((size_t)NB * 4);
    int*   gstart = (int*)take((size_t)(NG + 1) * 4);
    float* qstar  = (float*)take((size_t)NG * 2 * H2 * 4);

    int2* pairs = (int2*)sbuf;  // NB*CAP*8 = 15.2 MB, free until agg1 writes s1

    // CSR build (bucket-binned)
    bcur_init_kernel<<<(NB + 255) / 256, 256, 0, stream>>>(bcursor);
    bin_scatter_kernel<<<(E + CHUNK - 1) / CHUNK, 256, 0, stream>>>(ei, bcursor, pairs);
    csr_bucket_kernel<<<NB, 256, 0, stream>>>(pairs, bcursor, srcs, nrange);

    // graph ranges
    gstart_kernel<<<3, 256, 0, stream>>>(batch, gstart);

    // node feature pipeline
    int linGrid = (N + 63) / 64;
    lin_kernel<NF, H1, true, 1><<<linGrid, 256, 0, stream>>>(x, nfc_W, nfc_b, hbbuf, N);      // h1 (bf16)
    agg_kernel<<<(N + 3) / 4, 256, 0, stream>>>(hbbuf, nrange, srcs, sbuf);                   // s1 (fp32)
    lin_kernel<H1, H1, true, 1><<<linGrid, 256, 0, stream>>>(sbuf, gc1_W, gc1_b, hbbuf, N);   // h2 (bf16)
    agg_kernel<<<(N + 3) / 4, 256, 0, stream>>>(hbbuf, nrange, srcs, sbuf);                   // s2 (fp32)
    lin_kernel<H1, H2, true, 2><<<linGrid, 256, 0, stream>>>(sbuf, gc2_W, gc2_b, hn_out, N);  // normalized h

    // fused Set2Set (all 4 steps, one block per graph)
    set2set_kernel<<<NG, 256, 0, stream>>>(hn_out, gstart,
                                           l0_Wih, l0_Whh, l0_bih, l0_bhh,
                                           l1_Wih, l1_Whh, l1_bih, l1_bhh, qstar);

    // head
    fcout_kernel<<<2, 256, 0, stream>>>(qstar, fc1_W, fc1_b, fc2_W, fc2_b, out);
}

// Round 4
// 689.474 us; speedup vs baseline: 2.0959x; 1.1409x over previous
//
#include <hip/hip_runtime.h>
#include <hip/hip_bf16.h>
#include <math.h>

// Problem constants (fixed by the reference).
constexpr int N  = 100000;   // nodes
constexpr int E  = 1600000;  // edges
constexpr int NG = 512;      // graphs
constexpr int NF = 64;
constexpr int H1 = 128;
constexpr int H2 = 64;

// CSR bucket binning
constexpr int BW   = 256;                 // nodes per bucket (dst >> 8)
constexpr int NB   = (N + BW - 1) / BW;   // 391 buckets
constexpr int CAP  = 4864;                // per-bucket edge capacity (mean 4096 + 12 sigma)
constexpr int CHUNK = 8192;               // edges per bin_scatter block

// Set2Set LDS node cache
constexpr int MAXN = 416;                 // mean 195 + 15.8 sigma; global fallback beyond
constexpr int RST  = 68;                  // row stride in ushorts (34 dwords: bank stride 2, 8B-aligned rows)

__device__ __forceinline__ float gelu_f(float x) {
    return 0.5f * x * (1.0f + erff(x * 0.70710678118654752f));
}
__device__ __forceinline__ float sigmoid_f(float x) {
    return 1.0f / (1.0f + expf(-x));
}
__device__ __forceinline__ float waveAllSum(float v) {
    #pragma unroll
    for (int m = 32; m; m >>= 1) v += __shfl_xor(v, m);
    return v;
}
__device__ __forceinline__ unsigned short f2bf(float x) {
    __hip_bfloat16 b = __float2bfloat16(x);
    return *reinterpret_cast<unsigned short*>(&b);
}
__device__ __forceinline__ float bf_lo(unsigned int u) { return __uint_as_float(u << 16); }
__device__ __forceinline__ float bf_hi(unsigned int u) { return __uint_as_float(u & 0xffff0000u); }

// ---------------- CSR build, phase 0: init bucket cursors ----------------
__global__ __launch_bounds__(256) void bcur_init_kernel(int* __restrict__ bcursor) {
    int b = blockIdx.x * 256 + threadIdx.x;
    if (b < NB) bcursor[b] = b * CAP;
}

// ---------------- CSR build, phase 1: bin edges into bucket-strided (src,dst) pairs ----
__global__ __launch_bounds__(256) void bin_scatter_kernel(const int* __restrict__ ei,
                                                          int* __restrict__ bcursor,
                                                          int2* __restrict__ pairs) {
    __shared__ int hist[NB];
    __shared__ int start_s[NB];
    __shared__ int lcur[NB];
    int tid = threadIdx.x;
    int e0 = blockIdx.x * CHUNK;
    for (int b = tid; b < NB; b += 256) hist[b] = 0;
    __syncthreads();
    #pragma unroll 4
    for (int k = 0; k < CHUNK / 256; ++k) {
        int e = e0 + k * 256 + tid;
        if (e < E) atomicAdd(&hist[ei[E + e] >> 8], 1);
    }
    __syncthreads();
    for (int b = tid; b < NB; b += 256) {
        if (hist[b]) start_s[b] = atomicAdd(&bcursor[b], hist[b]);
        lcur[b] = 0;
    }
    __syncthreads();
    #pragma unroll 4
    for (int k = 0; k < CHUNK / 256; ++k) {
        int e = e0 + k * 256 + tid;
        if (e < E) {
            int d = ei[E + e];
            int s = ei[e];
            int b = d >> 8;
            int pos = start_s[b] + atomicAdd(&lcur[b], 1);
            if (pos < (b + 1) * CAP) pairs[pos] = make_int2(s, d);
        }
    }
}

// ---------------- CSR build, phase 2: per-bucket local CSR in LDS ----------------
__global__ __launch_bounds__(256) void csr_bucket_kernel(const int2* __restrict__ pairs,
                                                         const int* __restrict__ bcursor,
                                                         int* __restrict__ srcs,
                                                         int2* __restrict__ nrange) {
    __shared__ int cnt_l[256];
    __shared__ int cur_l[256];
    __shared__ int wt[4];
    int b = blockIdx.x;
    int tid = threadIdx.x;
    int base = b * CAP;
    int cnt = bcursor[b] - base;
    if (cnt > CAP) cnt = CAP;
    cnt_l[tid] = 0;
    __syncthreads();
    for (int i = tid; i < cnt; i += 256) {
        atomicAdd(&cnt_l[pairs[base + i].y & 255], 1);
    }
    __syncthreads();
    int v = cnt_l[tid];
    int lane = tid & 63, w = tid >> 6;
    int incl = v;
    #pragma unroll
    for (int off = 1; off < 64; off <<= 1) {
        int t = __shfl_up(incl, off);
        if (lane >= off) incl += t;
    }
    if (lane == 63) wt[w] = incl;
    __syncthreads();
    int add = 0;
    for (int i = 0; i < w; ++i) add += wt[i];
    int excl = add + incl - v;
    int node = b * 256 + tid;
    if (node < N) {
        nrange[node] = make_int2(base + excl, base + excl + v);
    }
    cur_l[tid] = excl;
    __syncthreads();
    for (int i = tid; i < cnt; i += 256) {
        int2 p = pairs[base + i];
        int d = p.y & 255;
        int pos = atomicAdd(&cur_l[d], 1);
        srcs[base + pos] = p.x;
    }
}

// ---------------- graph ranges via binary search (batch is sorted) ----------------
__global__ __launch_bounds__(256) void gstart_kernel(const int* __restrict__ batch, int* __restrict__ gstart) {
    int g = blockIdx.x * 256 + threadIdx.x;
    if (g > NG) return;
    if (g == NG) { gstart[NG] = N; return; }
    int lo = 0, hi = N;
    while (lo < hi) {
        int mid = (lo + hi) >> 1;
        if (batch[mid] < g) lo = mid + 1; else hi = mid;
    }
    gstart[g] = lo;
}

// ---------------- tiled fp32 linear ----------------
// OUT_MODE: 0 = fp32, 1 = bf16-packed, 2 = fp32 + row-L2-normalize (OD=64 only)
template <int ID, int OD, bool GELU, int OUT_MODE>
__global__ __launch_bounds__(256) void lin_kernel(const float* __restrict__ in,
                                                  const float* __restrict__ W,
                                                  const float* __restrict__ bias,
                                                  void* __restrict__ out_v, int nrows) {
    constexpr int KC = 64;
    constexpr int NCH = ID / KC;
    constexpr int TN = 64;
    constexpr int NPT = 8;
    constexpr int OPT = (TN * OD) / (256 * NPT);  // 128->4, 64->2
    constexpr int LS = KC + 2;
    __shared__ __align__(16) float xs[TN * LS];
    __shared__ __align__(16) float Wl[OD * LS];
    int tid = threadIdx.x;
    int nb = blockIdx.x * TN;
    int ng = tid & 7;
    int og = tid >> 3;
    float acc[NPT][OPT];
    #pragma unroll
    for (int i = 0; i < NPT; ++i)
        #pragma unroll
        for (int j = 0; j < OPT; ++j) acc[i][j] = 0.f;

    for (int c = 0; c < NCH; ++c) {
        int kb = c * KC;
        for (int i = tid; i < TN * KC; i += 256) {
            int nn = i / KC, f = i % KC;
            int row = nb + nn;
            xs[nn * LS + f] = (row < nrows) ? in[row * ID + kb + f] : 0.f;
        }
        for (int i = tid; i < OD * KC; i += 256) {
            int o = i / KC, f = i % KC;
            Wl[o * LS + f] = W[o * ID + kb + f];
        }
        __syncthreads();
        for (int f = 0; f < KC; f += 2) {
            float2 xv[NPT], wv[OPT];
            #pragma unroll
            for (int i = 0; i < NPT; ++i) xv[i] = *(const float2*)&xs[(ng + 8 * i) * LS + f];
            #pragma unroll
            for (int j = 0; j < OPT; ++j) wv[j] = *(const float2*)&Wl[(og * OPT + j) * LS + f];
            #pragma unroll
            for (int i = 0; i < NPT; ++i)
                #pragma unroll
                for (int j = 0; j < OPT; ++j) {
                    acc[i][j] += xv[i].x * wv[j].x;
                    acc[i][j] += xv[i].y * wv[j].y;
                }
        }
        __syncthreads();
    }

    if (OUT_MODE == 2) {
        float* st = xs;  // reuse as [64][65]
        #pragma unroll
        for (int i = 0; i < NPT; ++i) {
            int rl = ng + 8 * i;
            #pragma unroll
            for (int j = 0; j < OPT; ++j) {
                int o = og * OPT + j;
                float v = acc[i][j] + bias[o];
                if (GELU) v = gelu_f(v);
                st[rl * 65 + o] = ((nb + rl) < nrows) ? v : 0.f;
            }
        }
        __syncthreads();
        float* out = (float*)out_v;
        int w = tid >> 6, lane = tid & 63;
        for (int r = w * 16; r < w * 16 + 16; ++r) {
            int row = nb + r;
            float v = st[r * 65 + lane];
            float ss = waveAllSum(v * v);
            float denom = fmaxf(sqrtf(ss), 1e-12f);
            if (row < nrows) out[(size_t)row * 64 + lane] = v / denom;
        }
        return;
    }

    #pragma unroll
    for (int i = 0; i < NPT; ++i) {
        int row = nb + ng + 8 * i;
        if (row >= nrows) continue;
        float v[OPT];
        #pragma unroll
        for (int j = 0; j < OPT; ++j) {
            int o = og * OPT + j;
            v[j] = acc[i][j] + bias[o];
            if (GELU) v[j] = gelu_f(v[j]);
        }
        if (OUT_MODE == 1) {
            unsigned int u0 = (unsigned int)f2bf(v[0]) | ((unsigned int)f2bf(v[1]) << 16);
            if (OPT == 4) {
                unsigned int u1 = (unsigned int)f2bf(v[2]) | ((unsigned int)f2bf(v[3]) << 16);
                ((uint2*)out_v)[(size_t)row * (OD / 4) + og] = make_uint2(u0, u1);
            } else {
                ((unsigned int*)out_v)[(size_t)row * (OD / 2) + og] = u0;
            }
        } else {
            float* out = (float*)out_v;
            #pragma unroll
            for (int j = 0; j < OPT; ++j) out[(size_t)row * OD + og * OPT + j] = v[j];
        }
    }
}

// ---------------- GIN aggregation (bf16 table): out[n] = h[n] + sum h[src], H1=128 ----
__global__ __launch_bounds__(256) void agg_kernel(const unsigned int* __restrict__ hb,
                                                  const int2* __restrict__ nrange,
                                                  const int* __restrict__ srcs,
                                                  float* __restrict__ out) {
    int wave = threadIdx.x >> 6, lane = threadIdx.x & 63;
    int n = blockIdx.x * 4 + wave;
    if (n >= N) return;
    unsigned int u = hb[(size_t)n * 64 + lane];
    float accx = bf_lo(u);
    float accy = bf_hi(u);
    int2 rng = nrange[n];
    int s0 = rng.x;
    int deg = rng.y - rng.x;
    int pre = (lane < deg) ? srcs[s0 + lane] : 0;
    int m1 = deg < 64 ? deg : 64;
    for (int j = 0; j < m1; ++j) {
        int s = __shfl(pre, j);
        unsigned int uv = hb[(size_t)s * 64 + lane];
        accx += bf_lo(uv);
        accy += bf_hi(uv);
    }
    for (int j = 64; j < deg; ++j) {
        int s = srcs[s0 + j];
        unsigned int uv = hb[(size_t)s * 64 + lane];
        accx += bf_lo(uv);
        accy += bf_hi(uv);
    }
    ((float2*)out)[(size_t)n * 64 + lane] = make_float2(accx, accy);
}

// ---------------- fused Set2Set: one block per graph, LDS node cache, all 4 steps ----------------
__global__ __launch_bounds__(256) void set2set_kernel(const float* __restrict__ hn,
                                                      const int* __restrict__ gstart,
                                                      const float* __restrict__ Wih0, const float* __restrict__ Whh0,
                                                      const float* __restrict__ bih0, const float* __restrict__ bhh0,
                                                      const float* __restrict__ Wih1, const float* __restrict__ Whh1,
                                                      const float* __restrict__ bih1, const float* __restrict__ bhh1,
                                                      float* __restrict__ qstar_out) {
    __shared__ __align__(16) unsigned short hL[MAXN * RST];  // bf16 node rows, stride 68
    __shared__ float av[MAXN];                               // e, then unnormalized p
    __shared__ __align__(16) float qs[2 * H2];
    __shared__ __align__(16) float gates[256];
    __shared__ __align__(16) float h0v[H2], c0v[H2], h1v[H2], c1v[H2];
    __shared__ float red[4];
    __shared__ float rp[4][H2];
    __shared__ float sp[4];

    int g = blockIdx.x;
    int tid = threadIdx.x, w = tid >> 6, lane = tid & 63;
    int s0 = gstart[g], s1 = gstart[g + 1];
    int cnt = s1 - s0;
    int cL = cnt < MAXN ? cnt : MAXN;

    // stage this graph's rows into LDS as bf16 (coalesced float4 reads)
    for (int idx = tid; idx < cL * 16; idx += 256) {
        int n = idx >> 4, p4 = idx & 15;
        float4 v = *(const float4*)&hn[(size_t)(s0 + n) * 64 + p4 * 4];
        uint2 u;
        u.x = (unsigned int)f2bf(v.x) | ((unsigned int)f2bf(v.y) << 16);
        u.y = (unsigned int)f2bf(v.z) | ((unsigned int)f2bf(v.w) << 16);
        *(uint2*)&hL[n * RST + p4 * 4] = u;
    }
    if (tid < 2 * H2) qs[tid] = 0.f;
    if (tid < H2) { h0v[tid] = 0.f; c0v[tid] = 0.f; h1v[tid] = 0.f; c1v[tid] = 0.f; }
    __syncthreads();

    for (int step = 0; step < 4; ++step) {
        // ---- LSTM cell 0: gate row = tid; x = qs (128), h = h0v ----
        {
            float a = bih0[tid] + bhh0[tid];
            const float4* wi = (const float4*)(Wih0 + tid * 2 * H2);
            const float4* wh = (const float4*)(Whh0 + tid * H2);
            const float4* q4 = (const float4*)qs;
            const float4* h4 = (const float4*)h0v;
            #pragma unroll 8
            for (int k = 0; k < 2 * H2 / 4; ++k) {
                float4 wv = wi[k], xv = q4[k];
                a += wv.x * xv.x + wv.y * xv.y + wv.z * xv.z + wv.w * xv.w;
            }
            #pragma unroll 8
            for (int k = 0; k < H2 / 4; ++k) {
                float4 wv = wh[k], xv = h4[k];
                a += wv.x * xv.x + wv.y * xv.y + wv.z * xv.z + wv.w * xv.w;
            }
            gates[tid] = a;
        }
        __syncthreads();
        if (tid < H2) {
            float ii = sigmoid_f(gates[tid]), ff = sigmoid_f(gates[H2 + tid]);
            float gg = tanhf(gates[2 * H2 + tid]), oo = sigmoid_f(gates[3 * H2 + tid]);
            float c = ff * c0v[tid] + ii * gg;
            float h = oo * tanhf(c);
            c0v[tid] = c; h0v[tid] = h;
        }
        __syncthreads();
        // ---- LSTM cell 1 ----
        {
            float a = bih1[tid] + bhh1[tid];
            const float4* wi = (const float4*)(Wih1 + tid * H2);
            const float4* wh = (const float4*)(Whh1 + tid * H2);
            const float4* x4 = (const float4*)h0v;
            const float4* h4 = (const float4*)h1v;
            #pragma unroll 8
            for (int k = 0; k < H2 / 4; ++k) {
                float4 wv = wi[k], xv = x4[k];
                a += wv.x * xv.x + wv.y * xv.y + wv.z * xv.z + wv.w * xv.w;
            }
            #pragma unroll 8
            for (int k = 0; k < H2 / 4; ++k) {
                float4 wv = wh[k], xv = h4[k];
                a += wv.x * xv.x + wv.y * xv.y + wv.z * xv.z + wv.w * xv.w;
            }
            gates[tid] = a;
        }
        __syncthreads();
        if (tid < H2) {
            float ii = sigmoid_f(gates[tid]), ff = sigmoid_f(gates[H2 + tid]);
            float gg = tanhf(gates[2 * H2 + tid]), oo = sigmoid_f(gates[3 * H2 + tid]);
            float c = ff * c1v[tid] + ii * gg;
            float h = oo * tanhf(c);
            c1v[tid] = c; h1v[tid] = h;   // h1v == q
        }
        __syncthreads();

        // ---- attention e-phase: one THREAD per node, dot(h_n, q) from LDS ----
        float lm = -INFINITY;
        for (int i = tid; i < cnt; i += 256) {
            float e = 0.f;
            if (i < MAXN) {
                const uint2* row = (const uint2*)&hL[i * RST];
                #pragma unroll
                for (int p4 = 0; p4 < 16; ++p4) {
                    uint2 u = row[p4];
                    e += bf_lo(u.x) * h1v[p4 * 4 + 0];
                    e += bf_hi(u.x) * h1v[p4 * 4 + 1];
                    e += bf_lo(u.y) * h1v[p4 * 4 + 2];
                    e += bf_hi(u.y) * h1v[p4 * 4 + 3];
                }
                av[i] = e;
            } else {  // overflow fallback (statistically never)
                for (int f = 0; f < 64; ++f) e += hn[(size_t)(s0 + i) * 64 + f] * h1v[f];
            }
            lm = fmaxf(lm, e);
        }
        #pragma unroll
        for (int mm = 32; mm; mm >>= 1) lm = fmaxf(lm, __shfl_xor(lm, mm));
        if (lane == 0) red[w] = lm;
        __syncthreads();
        float m = fmaxf(fmaxf(red[0], red[1]), fmaxf(red[2], red[3]));

        // ---- p-phase: p = exp(e - m), block sum, store unnormalized p ----
        float ps = 0.f;
        for (int i = tid; i < cnt; i += 256) {
            float e;
            if (i < MAXN) e = av[i];
            else {
                e = 0.f;
                for (int f = 0; f < 64; ++f) e += hn[(size_t)(s0 + i) * 64 + f] * h1v[f];
            }
            float p = expf(e - m);
            ps += p;
            if (i < MAXN) av[i] = p;
        }
        ps = waveAllSum(ps);
        if (lane == 0) sp[w] = ps;
        __syncthreads();
        float s = sp[0] + sp[1] + sp[2] + sp[3];

        // ---- r-phase: feature = lane, nodes strided by wave; LDS conflict-free ----
        float racc = 0.f;
        for (int i = w; i < cL; i += 4) {
            unsigned short hv = hL[i * RST + lane];
            racc += av[i] * __uint_as_float(((unsigned int)hv) << 16);
        }
        // overflow nodes: recompute p wave-cooperatively from global (never taken)
        float qf = h1v[lane];
        for (int n = MAXN + w; n < cnt; n += 4) {
            float v = hn[(size_t)(s0 + n) * 64 + lane];
            float e = waveAllSum(v * qf);
            float p = expf(e - m);
            racc += p * v;
        }
        rp[w][lane] = racc;
        __syncthreads();
        if (tid < H2) {
            float r = 0.f;
            if (cnt > 0) {
                r = (rp[0][tid] + rp[1][tid] + rp[2][tid] + rp[3][tid]) / (s + 1e-16f);
            }
            qs[tid] = h1v[tid];
            qs[H2 + tid] = r;
        }
        __syncthreads();
    }
    if (tid < 2 * H2) qstar_out[g * 2 * H2 + tid] = qs[tid];
}

// ---------------- output head: z = fc2(gelu(fc1(q_star))) ----------------
__global__ __launch_bounds__(256) void fcout_kernel(const float* __restrict__ q_star,
                                                    const float* __restrict__ W1, const float* __restrict__ b1,
                                                    const float* __restrict__ W2, const float* __restrict__ b2,
                                                    float* __restrict__ z) {
    __shared__ float W1l[32 * 128];
    __shared__ float b1l[32], W2l[32];
    int tid = threadIdx.x;
    for (int i = tid; i < 32 * 128; i += 256) W1l[i] = W1[i];
    if (tid < 32) { b1l[tid] = b1[tid]; W2l[tid] = W2[tid]; }
    __syncthreads();
    int g = blockIdx.x * 256 + tid;
    float acc[32];
    #pragma unroll
    for (int j = 0; j < 32; ++j) acc[j] = b1l[j];
    for (int k = 0; k < 128; ++k) {
        float qv = q_star[g * 128 + k];
        #pragma unroll
        for (int j = 0; j < 32; ++j) acc[j] += qv * W1l[j * 128 + k];
    }
    float zv = b2[0];
    #pragma unroll
    for (int j = 0; j < 32; ++j) zv += gelu_f(acc[j]) * W2l[j];
    z[g] = zv;
}

extern "C" void kernel_launch(void* const* d_in, const int* in_sizes, int n_in,
                              void* d_out, int out_size, void* d_ws, size_t ws_size,
                              hipStream_t stream) {
    const float* x       = (const float*)d_in[0];
    const int*   ei      = (const int*)d_in[1];
    const int*   batch   = (const int*)d_in[2];
    const float* nfc_W   = (const float*)d_in[3];
    const float* nfc_b   = (const float*)d_in[4];
    const float* gc1_W   = (const float*)d_in[5];
    const float* gc1_b   = (const float*)d_in[6];
    const float* gc2_W   = (const float*)d_in[7];
    const float* gc2_b   = (const float*)d_in[8];
    const float* l0_Wih  = (const float*)d_in[9];
    const float* l0_Whh  = (const float*)d_in[10];
    const float* l0_bih  = (const float*)d_in[11];
    const float* l0_bhh  = (const float*)d_in[12];
    const float* l1_Wih  = (const float*)d_in[13];
    const float* l1_Whh  = (const float*)d_in[14];
    const float* l1_bih  = (const float*)d_in[15];
    const float* l1_bhh  = (const float*)d_in[16];
    const float* fc1_W   = (const float*)d_in[17];
    const float* fc1_b   = (const float*)d_in[18];
    const float* fc2_W   = (const float*)d_in[19];
    const float* fc2_b   = (const float*)d_in[20];

    float* out = (float*)d_out;          // [0,512): z ; [512, 512+N*64): normalized h
    float* hn_out = out + NG;

    char* p = (char*)d_ws;
    auto take = [&](size_t bytes) {
        char* r = p;
        p += (bytes + 255) & ~size_t(255);
        return r;
    };
    float*        sbuf  = (float*)take((size_t)N * H1 * 4);        // s1 / s2 (fp32); aliased as pairs pre-lin
    unsigned int* hbbuf = (unsigned int*)take((size_t)N * H1 * 2); // h1 / h2 (bf16-packed)
    int*   srcs   = (int*)take((size_t)NB * CAP * 4);
    int2*  nrange = (int2*)take((size_t)N * 8);
    int*   bcursor= (int*)take((size_t)NB * 4);
    int*   gstart = (int*)take((size_t)(NG + 1) * 4);
    float* qstar  = (float*)take((size_t)NG * 2 * H2 * 4);

    int2* pairs = (int2*)sbuf;  // NB*CAP*8 = 15.2 MB, free until agg1 writes s1

    // CSR build (bucket-binned)
    bcur_init_kernel<<<(NB + 255) / 256, 256, 0, stream>>>(bcursor);
    bin_scatter_kernel<<<(E + CHUNK - 1) / CHUNK, 256, 0, stream>>>(ei, bcursor, pairs);
    csr_bucket_kernel<<<NB, 256, 0, stream>>>(pairs, bcursor, srcs, nrange);

    // graph ranges
    gstart_kernel<<<3, 256, 0, stream>>>(batch, gstart);

    // node feature pipeline
    int linGrid = (N + 63) / 64;
    lin_kernel<NF, H1, true, 1><<<linGrid, 256, 0, stream>>>(x, nfc_W, nfc_b, hbbuf, N);      // h1 (bf16)
    agg_kernel<<<(N + 3) / 4, 256, 0, stream>>>(hbbuf, nrange, srcs, sbuf);                   // s1 (fp32)
    lin_kernel<H1, H1, true, 1><<<linGrid, 256, 0, stream>>>(sbuf, gc1_W, gc1_b, hbbuf, N);   // h2 (bf16)
    agg_kernel<<<(N + 3) / 4, 256, 0, stream>>>(hbbuf, nrange, srcs, sbuf);                   // s2 (fp32)
    lin_kernel<H1, H2, true, 2><<<linGrid, 256, 0, stream>>>(sbuf, gc2_W, gc2_b, hn_out, N);  // normalized h

    // fused Set2Set (all 4 steps, one block per graph, LDS node cache)
    set2set_kernel<<<NG, 256, 0, stream>>>(hn_out, gstart,
                                           l0_Wih, l0_Whh, l0_bih, l0_bhh,
                                           l1_Wih, l1_Whh, l1_bih, l1_bhh, qstar);

    // head
    fcout_kernel<<<2, 256, 0, stream>>>(qstar, fc1_W, fc1_b, fc2_W, fc2_b, out);
}

// Round 5
// 509.732 us; speedup vs baseline: 2.8349x; 1.3526x over previous
//
#include <hip/hip_runtime.h>
#include <hip/hip_bf16.h>
#include <math.h>

// Problem constants (fixed by the reference).
constexpr int N  = 100000;   // nodes
constexpr int E  = 1600000;  // edges
constexpr int NG = 512;      // graphs
constexpr int NF = 64;
constexpr int H1 = 128;
constexpr int H2 = 64;

// CSR bucket binning
constexpr int BW   = 256;                 // nodes per bucket (dst >> 8)
constexpr int NB   = (N + BW - 1) / BW;   // 391 buckets
constexpr int CAP  = 4864;                // per-bucket edge capacity (mean 4096 + 12 sigma)
constexpr int CHUNK = 8192;               // edges per bin_scatter block

// Set2Set LDS node cache
constexpr int MAXN = 416;                 // mean 195 + 15.8 sigma; global fallback beyond
constexpr int RST  = 68;                  // row stride in ushorts

typedef __attribute__((ext_vector_type(8))) short short8;
typedef __attribute__((ext_vector_type(4))) float f32x4;

__device__ __forceinline__ float gelu_f(float x) {
    return 0.5f * x * (1.0f + erff(x * 0.70710678118654752f));
}
__device__ __forceinline__ float sigmoid_f(float x) {
    return 1.0f / (1.0f + expf(-x));
}
__device__ __forceinline__ float waveAllSum(float v) {
    #pragma unroll
    for (int m = 32; m; m >>= 1) v += __shfl_xor(v, m);
    return v;
}
__device__ __forceinline__ unsigned short f2bf(float x) {
    __hip_bfloat16 b = __float2bfloat16(x);
    return *reinterpret_cast<unsigned short*>(&b);
}
__device__ __forceinline__ float bf2f(unsigned short u) {
    return __uint_as_float(((unsigned int)u) << 16);
}
__device__ __forceinline__ float bf_lo(unsigned int u) { return __uint_as_float(u << 16); }
__device__ __forceinline__ float bf_hi(unsigned int u) { return __uint_as_float(u & 0xffff0000u); }

// split v into bf16 hi + bf16 lo (v ~= hi + lo)
__device__ __forceinline__ void bfsplit(float v, unsigned short& hi, unsigned short& lo) {
    hi = f2bf(v);
    lo = f2bf(v - bf2f(hi));
}

// ---------------- CSR build, phase 0: init bucket cursors ----------------
__global__ __launch_bounds__(256) void bcur_init_kernel(int* __restrict__ bcursor) {
    int b = blockIdx.x * 256 + threadIdx.x;
    if (b < NB) bcursor[b] = b * CAP;
}

// ---------------- CSR build, phase 1: bin edges into bucket-strided (src,dst) pairs ----
__global__ __launch_bounds__(256) void bin_scatter_kernel(const int* __restrict__ ei,
                                                          int* __restrict__ bcursor,
                                                          int2* __restrict__ pairs) {
    __shared__ int hist[NB];
    __shared__ int start_s[NB];
    __shared__ int lcur[NB];
    int tid = threadIdx.x;
    int e0 = blockIdx.x * CHUNK;
    for (int b = tid; b < NB; b += 256) hist[b] = 0;
    __syncthreads();
    #pragma unroll 4
    for (int k = 0; k < CHUNK / 256; ++k) {
        int e = e0 + k * 256 + tid;
        if (e < E) atomicAdd(&hist[ei[E + e] >> 8], 1);
    }
    __syncthreads();
    for (int b = tid; b < NB; b += 256) {
        if (hist[b]) start_s[b] = atomicAdd(&bcursor[b], hist[b]);
        lcur[b] = 0;
    }
    __syncthreads();
    #pragma unroll 4
    for (int k = 0; k < CHUNK / 256; ++k) {
        int e = e0 + k * 256 + tid;
        if (e < E) {
            int d = ei[E + e];
            int s = ei[e];
            int b = d >> 8;
            int pos = start_s[b] + atomicAdd(&lcur[b], 1);
            if (pos < (b + 1) * CAP) pairs[pos] = make_int2(s, d);
        }
    }
}

// ---------------- CSR build, phase 2: per-bucket local CSR in LDS ----------------
__global__ __launch_bounds__(256) void csr_bucket_kernel(const int2* __restrict__ pairs,
                                                         const int* __restrict__ bcursor,
                                                         int* __restrict__ srcs,
                                                         int2* __restrict__ nrange) {
    __shared__ int cnt_l[256];
    __shared__ int cur_l[256];
    __shared__ int wt[4];
    int b = blockIdx.x;
    int tid = threadIdx.x;
    int base = b * CAP;
    int cnt = bcursor[b] - base;
    if (cnt > CAP) cnt = CAP;
    cnt_l[tid] = 0;
    __syncthreads();
    for (int i = tid; i < cnt; i += 256) {
        atomicAdd(&cnt_l[pairs[base + i].y & 255], 1);
    }
    __syncthreads();
    int v = cnt_l[tid];
    int lane = tid & 63, w = tid >> 6;
    int incl = v;
    #pragma unroll
    for (int off = 1; off < 64; off <<= 1) {
        int t = __shfl_up(incl, off);
        if (lane >= off) incl += t;
    }
    if (lane == 63) wt[w] = incl;
    __syncthreads();
    int add = 0;
    for (int i = 0; i < w; ++i) add += wt[i];
    int excl = add + incl - v;
    int node = b * 256 + tid;
    if (node < N) {
        nrange[node] = make_int2(base + excl, base + excl + v);
    }
    cur_l[tid] = excl;
    __syncthreads();
    for (int i = tid; i < cnt; i += 256) {
        int2 p = pairs[base + i];
        int d = p.y & 255;
        int pos = atomicAdd(&cur_l[d], 1);
        srcs[base + pos] = p.x;
    }
}

// ---------------- graph ranges via binary search (batch is sorted) ----------------
__global__ __launch_bounds__(256) void gstart_kernel(const int* __restrict__ batch, int* __restrict__ gstart) {
    int g = blockIdx.x * 256 + threadIdx.x;
    if (g > NG) return;
    if (g == NG) { gstart[NG] = N; return; }
    int lo = 0, hi = N;
    while (lo < hi) {
        int mid = (lo + hi) >> 1;
        if (batch[mid] < g) lo = mid + 1; else hi = mid;
    }
    gstart[g] = lo;
}

// ---------------- MFMA bf16x3 linear: out = act(in @ W.T + b) ----------------
// Block tile: 128 rows x OD cols. 4 waves, each wave 32 rows (2x 16-row frags).
// bf16x3: A,W split into hi+lo bf16; D += Ah*Wh + Ah*Wl + Al*Wh  (~fp32 accuracy).
// OUT_MODE: 1 = gelu + bf16-pack table, 2 = gelu + row-L2-normalize + fp32 (OD=64)
template <int ID, int OD, int OUT_MODE>
__global__ __launch_bounds__(256) void lin_mfma_kernel(const float* __restrict__ in,
                                                       const float* __restrict__ W,
                                                       const float* __restrict__ bias,
                                                       void* __restrict__ out_v, int nrows) {
    constexpr int KC = 32;                 // k per chunk
    constexpr int NCH = ID / KC;
    constexpr int AST = 40;                // LDS row stride (ushorts): 16B-aligned rows, staggered banks
    constexpr int NCT = OD / 16;           // col tiles per wave
    constexpr int LDSU = 2 * 128 * AST + 2 * OD * AST;
    __shared__ __align__(16) unsigned short lds[LDSU];
    unsigned short* Ahi = lds;
    unsigned short* Alo = lds + 128 * AST;
    unsigned short* Whi = lds + 2 * 128 * AST;
    unsigned short* Wlo = lds + 2 * 128 * AST + OD * AST;

    int tid = threadIdx.x;
    int w = tid >> 6, lane = tid & 63;
    int m15 = lane & 15, quad = lane >> 4;
    int nb = blockIdx.x * 128;

    f32x4 acc[2][NCT];
    #pragma unroll
    for (int rt = 0; rt < 2; ++rt)
        #pragma unroll
        for (int ct = 0; ct < NCT; ++ct) acc[rt][ct] = (f32x4)0.f;

    for (int c = 0; c < NCH; ++c) {
        int kb = c * KC;
        // stage A chunk: 128 rows x 32 k (float4 loads, bf16 hi/lo split)
        #pragma unroll
        for (int it = 0; it < 4; ++it) {
            int f4 = it * 256 + tid;       // 1024 float4 = 128*32 floats
            int row = f4 >> 3, kq = (f4 & 7) * 4;
            float4 v = make_float4(0.f, 0.f, 0.f, 0.f);
            if (nb + row < nrows) v = *(const float4*)&in[(size_t)(nb + row) * ID + kb + kq];
            unsigned short h0, h1, h2, h3, l0, l1, l2, l3;
            bfsplit(v.x, h0, l0); bfsplit(v.y, h1, l1);
            bfsplit(v.z, h2, l2); bfsplit(v.w, h3, l3);
            uint2 uh, ul;
            uh.x = (unsigned int)h0 | ((unsigned int)h1 << 16);
            uh.y = (unsigned int)h2 | ((unsigned int)h3 << 16);
            ul.x = (unsigned int)l0 | ((unsigned int)l1 << 16);
            ul.y = (unsigned int)l2 | ((unsigned int)l3 << 16);
            *(uint2*)&Ahi[row * AST + kq] = uh;
            *(uint2*)&Alo[row * AST + kq] = ul;
        }
        // stage W chunk: OD rows x 32 k
        #pragma unroll
        for (int it = 0; it < OD / 32; ++it) {
            int f4 = it * 256 + tid;
            int o = f4 >> 3, kq = (f4 & 7) * 4;
            float4 v = *(const float4*)&W[(size_t)o * ID + kb + kq];
            unsigned short h0, h1, h2, h3, l0, l1, l2, l3;
            bfsplit(v.x, h0, l0); bfsplit(v.y, h1, l1);
            bfsplit(v.z, h2, l2); bfsplit(v.w, h3, l3);
            uint2 uh, ul;
            uh.x = (unsigned int)h0 | ((unsigned int)h1 << 16);
            uh.y = (unsigned int)h2 | ((unsigned int)h3 << 16);
            ul.x = (unsigned int)l0 | ((unsigned int)l1 << 16);
            ul.y = (unsigned int)l2 | ((unsigned int)l3 << 16);
            *(uint2*)&Whi[o * AST + kq] = uh;
            *(uint2*)&Wlo[o * AST + kq] = ul;
        }
        __syncthreads();

        // A fragments: row = wavebase + rt*16 + m15, k = quad*8 + j
        short8 ah0 = *(const short8*)&Ahi[(w * 32 + m15) * AST + quad * 8];
        short8 ah1 = *(const short8*)&Ahi[(w * 32 + 16 + m15) * AST + quad * 8];
        short8 al0 = *(const short8*)&Alo[(w * 32 + m15) * AST + quad * 8];
        short8 al1 = *(const short8*)&Alo[(w * 32 + 16 + m15) * AST + quad * 8];
        #pragma unroll
        for (int ct = 0; ct < NCT; ++ct) {
            short8 bh = *(const short8*)&Whi[(ct * 16 + m15) * AST + quad * 8];
            short8 bl = *(const short8*)&Wlo[(ct * 16 + m15) * AST + quad * 8];
            acc[0][ct] = __builtin_amdgcn_mfma_f32_16x16x32_bf16(ah0, bh, acc[0][ct], 0, 0, 0);
            acc[0][ct] = __builtin_amdgcn_mfma_f32_16x16x32_bf16(ah0, bl, acc[0][ct], 0, 0, 0);
            acc[0][ct] = __builtin_amdgcn_mfma_f32_16x16x32_bf16(al0, bh, acc[0][ct], 0, 0, 0);
            acc[1][ct] = __builtin_amdgcn_mfma_f32_16x16x32_bf16(ah1, bh, acc[1][ct], 0, 0, 0);
            acc[1][ct] = __builtin_amdgcn_mfma_f32_16x16x32_bf16(ah1, bl, acc[1][ct], 0, 0, 0);
            acc[1][ct] = __builtin_amdgcn_mfma_f32_16x16x32_bf16(al1, bh, acc[1][ct], 0, 0, 0);
        }
        __syncthreads();
    }

    // bias per col tile
    float bcol[NCT];
    #pragma unroll
    for (int ct = 0; ct < NCT; ++ct) bcol[ct] = bias[ct * 16 + m15];

    if (OUT_MODE == 1) {
        // gelu + bf16 pack via LDS restage, coalesced uint4 writes
        constexpr int EPS = OD + 8;
        unsigned short* ep = lds;  // 128*EPS <= LDSU
        #pragma unroll
        for (int rt = 0; rt < 2; ++rt)
            #pragma unroll
            for (int ct = 0; ct < NCT; ++ct)
                #pragma unroll
                for (int r = 0; r < 4; ++r) {
                    int rl = w * 32 + rt * 16 + quad * 4 + r;
                    float v = gelu_f(acc[rt][ct][r] + bcol[ct]);
                    ep[rl * EPS + ct * 16 + m15] = f2bf(v);
                }
        __syncthreads();
        constexpr int U4 = 128 * OD / 8;
        for (int i = tid; i < U4; i += 256) {
            int row = i / (OD / 8);
            int off = (i % (OD / 8)) * 8;
            int grow = nb + row;
            if (grow < nrows) {
                uint4 v = *(const uint4*)&ep[row * EPS + off];
                *(uint4*)((unsigned short*)out_v + (size_t)grow * OD + off) = v;
            }
        }
    } else {
        // gelu + row L2 normalize (OD = 64): row lives in the 16 lanes of a quad
        float* out = (float*)out_v;
        #pragma unroll
        for (int rt = 0; rt < 2; ++rt) {
            #pragma unroll
            for (int r = 0; r < 4; ++r) {
                float vv[NCT];
                float ss = 0.f;
                #pragma unroll
                for (int ct = 0; ct < NCT; ++ct) {
                    vv[ct] = gelu_f(acc[rt][ct][r] + bcol[ct]);
                    ss += vv[ct] * vv[ct];
                }
                #pragma unroll
                for (int mm = 1; mm < 16; mm <<= 1) ss += __shfl_xor(ss, mm);
                float denom = fmaxf(sqrtf(ss), 1e-12f);
                int grow = nb + w * 32 + rt * 16 + quad * 4 + r;
                if (grow < nrows) {
                    #pragma unroll
                    for (int ct = 0; ct < NCT; ++ct)
                        out[(size_t)grow * OD + ct * 16 + m15] = vv[ct] / denom;
                }
            }
        }
    }
}

// ---------------- GIN aggregation (bf16 table): out[n] = h[n] + sum h[src], H1=128 ----
__global__ __launch_bounds__(256) void agg_kernel(const unsigned int* __restrict__ hb,
                                                  const int2* __restrict__ nrange,
                                                  const int* __restrict__ srcs,
                                                  float* __restrict__ out) {
    int wave = threadIdx.x >> 6, lane = threadIdx.x & 63;
    int n = blockIdx.x * 4 + wave;
    if (n >= N) return;
    unsigned int u = hb[(size_t)n * 64 + lane];
    float accx = bf_lo(u);
    float accy = bf_hi(u);
    int2 rng = nrange[n];
    int s0 = rng.x;
    int deg = rng.y - rng.x;
    int pre = (lane < deg) ? srcs[s0 + lane] : 0;
    int m1 = deg < 64 ? deg : 64;
    int j = 0;
    for (; j + 4 <= m1; j += 4) {   // 4 independent loads per iter -> MLP
        int sa = __shfl(pre, j);
        int sb = __shfl(pre, j + 1);
        int sc = __shfl(pre, j + 2);
        int sd = __shfl(pre, j + 3);
        unsigned int ua = hb[(size_t)sa * 64 + lane];
        unsigned int ub = hb[(size_t)sb * 64 + lane];
        unsigned int uc = hb[(size_t)sc * 64 + lane];
        unsigned int ud = hb[(size_t)sd * 64 + lane];
        accx += bf_lo(ua); accy += bf_hi(ua);
        accx += bf_lo(ub); accy += bf_hi(ub);
        accx += bf_lo(uc); accy += bf_hi(uc);
        accx += bf_lo(ud); accy += bf_hi(ud);
    }
    for (; j < m1; ++j) {
        int s = __shfl(pre, j);
        unsigned int uv = hb[(size_t)s * 64 + lane];
        accx += bf_lo(uv);
        accy += bf_hi(uv);
    }
    for (j = 64; j < deg; ++j) {
        int s = srcs[s0 + j];
        unsigned int uv = hb[(size_t)s * 64 + lane];
        accx += bf_lo(uv);
        accy += bf_hi(uv);
    }
    ((float2*)out)[(size_t)n * 64 + lane] = make_float2(accx, accy);
}

// ---------------- fused Set2Set: one block per graph, LDS node cache, all 4 steps ----------------
__global__ __launch_bounds__(256) void set2set_kernel(const float* __restrict__ hn,
                                                      const int* __restrict__ gstart,
                                                      const float* __restrict__ Wih0, const float* __restrict__ Whh0,
                                                      const float* __restrict__ bih0, const float* __restrict__ bhh0,
                                                      const float* __restrict__ Wih1, const float* __restrict__ Whh1,
                                                      const float* __restrict__ bih1, const float* __restrict__ bhh1,
                                                      float* __restrict__ qstar_out) {
    __shared__ __align__(16) unsigned short hL[MAXN * RST];  // bf16 node rows, stride 68
    __shared__ float av[MAXN];                               // e, then unnormalized p
    __shared__ __align__(16) float qs[2 * H2];
    __shared__ __align__(16) float gates[256];
    __shared__ __align__(16) float h0v[H2], c0v[H2], h1v[H2], c1v[H2];
    __shared__ float red[4];
    __shared__ float rp[4][H2];
    __shared__ float sp[4];

    int g = blockIdx.x;
    int tid = threadIdx.x, w = tid >> 6, lane = tid & 63;
    int s0 = gstart[g], s1 = gstart[g + 1];
    int cnt = s1 - s0;
    int cL = cnt < MAXN ? cnt : MAXN;

    for (int idx = tid; idx < cL * 16; idx += 256) {
        int n = idx >> 4, p4 = idx & 15;
        float4 v = *(const float4*)&hn[(size_t)(s0 + n) * 64 + p4 * 4];
        uint2 u;
        u.x = (unsigned int)f2bf(v.x) | ((unsigned int)f2bf(v.y) << 16);
        u.y = (unsigned int)f2bf(v.z) | ((unsigned int)f2bf(v.w) << 16);
        *(uint2*)&hL[n * RST + p4 * 4] = u;
    }
    if (tid < 2 * H2) qs[tid] = 0.f;
    if (tid < H2) { h0v[tid] = 0.f; c0v[tid] = 0.f; h1v[tid] = 0.f; c1v[tid] = 0.f; }
    __syncthreads();

    for (int step = 0; step < 4; ++step) {
        {
            float a = bih0[tid] + bhh0[tid];
            const float4* wi = (const float4*)(Wih0 + tid * 2 * H2);
            const float4* wh = (const float4*)(Whh0 + tid * H2);
            const float4* q4 = (const float4*)qs;
            const float4* h4 = (const float4*)h0v;
            #pragma unroll 8
            for (int k = 0; k < 2 * H2 / 4; ++k) {
                float4 wv = wi[k], xv = q4[k];
                a += wv.x * xv.x + wv.y * xv.y + wv.z * xv.z + wv.w * xv.w;
            }
            #pragma unroll 8
            for (int k = 0; k < H2 / 4; ++k) {
                float4 wv = wh[k], xv = h4[k];
                a += wv.x * xv.x + wv.y * xv.y + wv.z * xv.z + wv.w * xv.w;
            }
            gates[tid] = a;
        }
        __syncthreads();
        if (tid < H2) {
            float ii = sigmoid_f(gates[tid]), ff = sigmoid_f(gates[H2 + tid]);
            float gg = tanhf(gates[2 * H2 + tid]), oo = sigmoid_f(gates[3 * H2 + tid]);
            float c = ff * c0v[tid] + ii * gg;
            float h = oo * tanhf(c);
            c0v[tid] = c; h0v[tid] = h;
        }
        __syncthreads();
        {
            float a = bih1[tid] + bhh1[tid];
            const float4* wi = (const float4*)(Wih1 + tid * H2);
            const float4* wh = (const float4*)(Whh1 + tid * H2);
            const float4* x4 = (const float4*)h0v;
            const float4* h4 = (const float4*)h1v;
            #pragma unroll 8
            for (int k = 0; k < H2 / 4; ++k) {
                float4 wv = wi[k], xv = x4[k];
                a += wv.x * xv.x + wv.y * xv.y + wv.z * xv.z + wv.w * xv.w;
            }
            #pragma unroll 8
            for (int k = 0; k < H2 / 4; ++k) {
                float4 wv = wh[k], xv = h4[k];
                a += wv.x * xv.x + wv.y * xv.y + wv.z * xv.z + wv.w * xv.w;
            }
            gates[tid] = a;
        }
        __syncthreads();
        if (tid < H2) {
            float ii = sigmoid_f(gates[tid]), ff = sigmoid_f(gates[H2 + tid]);
            float gg = tanhf(gates[2 * H2 + tid]), oo = sigmoid_f(gates[3 * H2 + tid]);
            float c = ff * c1v[tid] + ii * gg;
            float h = oo * tanhf(c);
            c1v[tid] = c; h1v[tid] = h;
        }
        __syncthreads();

        float lm = -INFINITY;
        for (int i = tid; i < cnt; i += 256) {
            float e = 0.f;
            if (i < MAXN) {
                const uint2* row = (const uint2*)&hL[i * RST];
                #pragma unroll
                for (int p4 = 0; p4 < 16; ++p4) {
                    uint2 u = row[p4];
                    e += bf_lo(u.x) * h1v[p4 * 4 + 0];
                    e += bf_hi(u.x) * h1v[p4 * 4 + 1];
                    e += bf_lo(u.y) * h1v[p4 * 4 + 2];
                    e += bf_hi(u.y) * h1v[p4 * 4 + 3];
                }
                av[i] = e;
            } else {
                for (int f = 0; f < 64; ++f) e += hn[(size_t)(s0 + i) * 64 + f] * h1v[f];
            }
            lm = fmaxf(lm, e);
        }
        #pragma unroll
        for (int mm = 32; mm; mm >>= 1) lm = fmaxf(lm, __shfl_xor(lm, mm));
        if (lane == 0) red[w] = lm;
        __syncthreads();
        float m = fmaxf(fmaxf(red[0], red[1]), fmaxf(red[2], red[3]));

        float ps = 0.f;
        for (int i = tid; i < cnt; i += 256) {
            float e;
            if (i < MAXN) e = av[i];
            else {
                e = 0.f;
                for (int f = 0; f < 64; ++f) e += hn[(size_t)(s0 + i) * 64 + f] * h1v[f];
            }
            float p = expf(e - m);
            ps += p;
            if (i < MAXN) av[i] = p;
        }
        ps = waveAllSum(ps);
        if (lane == 0) sp[w] = ps;
        __syncthreads();
        float s = sp[0] + sp[1] + sp[2] + sp[3];

        float racc = 0.f;
        for (int i = w; i < cL; i += 4) {
            unsigned short hv = hL[i * RST + lane];
            racc += av[i] * bf2f(hv);
        }
        float qf = h1v[lane];
        for (int n = MAXN + w; n < cnt; n += 4) {
            float v = hn[(size_t)(s0 + n) * 64 + lane];
            float e = waveAllSum(v * qf);
            float p = expf(e - m);
            racc += p * v;
        }
        rp[w][lane] = racc;
        __syncthreads();
        if (tid < H2) {
            float r = 0.f;
            if (cnt > 0) {
                r = (rp[0][tid] + rp[1][tid] + rp[2][tid] + rp[3][tid]) / (s + 1e-16f);
            }
            qs[tid] = h1v[tid];
            qs[H2 + tid] = r;
        }
        __syncthreads();
    }
    if (tid < 2 * H2) qstar_out[g * 2 * H2 + tid] = qs[tid];
}

// ---------------- output head: z = fc2(gelu(fc1(q_star))) ----------------
__global__ __launch_bounds__(256) void fcout_kernel(const float* __restrict__ q_star,
                                                    const float* __restrict__ W1, const float* __restrict__ b1,
                                                    const float* __restrict__ W2, const float* __restrict__ b2,
                                                    float* __restrict__ z) {
    __shared__ float W1l[32 * 128];
    __shared__ float b1l[32], W2l[32];
    int tid = threadIdx.x;
    for (int i = tid; i < 32 * 128; i += 256) W1l[i] = W1[i];
    if (tid < 32) { b1l[tid] = b1[tid]; W2l[tid] = W2[tid]; }
    __syncthreads();
    int g = blockIdx.x * 256 + tid;
    float acc[32];
    #pragma unroll
    for (int j = 0; j < 32; ++j) acc[j] = b1l[j];
    for (int k = 0; k < 128; ++k) {
        float qv = q_star[g * 128 + k];
        #pragma unroll
        for (int j = 0; j < 32; ++j) acc[j] += qv * W1l[j * 128 + k];
    }
    float zv = b2[0];
    #pragma unroll
    for (int j = 0; j < 32; ++j) zv += gelu_f(acc[j]) * W2l[j];
    z[g] = zv;
}

extern "C" void kernel_launch(void* const* d_in, const int* in_sizes, int n_in,
                              void* d_out, int out_size, void* d_ws, size_t ws_size,
                              hipStream_t stream) {
    const float* x       = (const float*)d_in[0];
    const int*   ei      = (const int*)d_in[1];
    const int*   batch   = (const int*)d_in[2];
    const float* nfc_W   = (const float*)d_in[3];
    const float* nfc_b   = (const float*)d_in[4];
    const float* gc1_W   = (const float*)d_in[5];
    const float* gc1_b   = (const float*)d_in[6];
    const float* gc2_W   = (const float*)d_in[7];
    const float* gc2_b   = (const float*)d_in[8];
    const float* l0_Wih  = (const float*)d_in[9];
    const float* l0_Whh  = (const float*)d_in[10];
    const float* l0_bih  = (const float*)d_in[11];
    const float* l0_bhh  = (const float*)d_in[12];
    const float* l1_Wih  = (const float*)d_in[13];
    const float* l1_Whh  = (const float*)d_in[14];
    const float* l1_bih  = (const float*)d_in[15];
    const float* l1_bhh  = (const float*)d_in[16];
    const float* fc1_W   = (const float*)d_in[17];
    const float* fc1_b   = (const float*)d_in[18];
    const float* fc2_W   = (const float*)d_in[19];
    const float* fc2_b   = (const float*)d_in[20];

    float* out = (float*)d_out;          // [0,512): z ; [512, 512+N*64): normalized h
    float* hn_out = out + NG;

    char* p = (char*)d_ws;
    auto take = [&](size_t bytes) {
        char* r = p;
        p += (bytes + 255) & ~size_t(255);
        return r;
    };
    float*        sbuf  = (float*)take((size_t)N * H1 * 4);        // s1 / s2 (fp32); aliased as pairs pre-lin
    unsigned int* hbbuf = (unsigned int*)take((size_t)N * H1 * 2); // h1 / h2 (bf16-packed)
    int*   srcs   = (int*)take((size_t)NB * CAP * 4);
    int2*  nrange = (int2*)take((size_t)N * 8);
    int*   bcursor= (int*)take((size_t)NB * 4);
    int*   gstart = (int*)take((size_t)(NG + 1) * 4);
    float* qstar  = (float*)take((size_t)NG * 2 * H2 * 4);

    int2* pairs = (int2*)sbuf;  // NB*CAP*8 = 15.2 MB, free until agg1 writes s1

    // CSR build (bucket-binned)
    bcur_init_kernel<<<(NB + 255) / 256, 256, 0, stream>>>(bcursor);
    bin_scatter_kernel<<<(E + CHUNK - 1) / CHUNK, 256, 0, stream>>>(ei, bcursor, pairs);
    csr_bucket_kernel<<<NB, 256, 0, stream>>>(pairs, bcursor, srcs, nrange);

    // graph ranges
    gstart_kernel<<<3, 256, 0, stream>>>(batch, gstart);

    // node feature pipeline (MFMA bf16x3 linears)
    int mfmaGrid = (N + 127) / 128;
    lin_mfma_kernel<NF, H1, 1><<<mfmaGrid, 256, 0, stream>>>(x, nfc_W, nfc_b, hbbuf, N);      // h1 (bf16)
    agg_kernel<<<(N + 3) / 4, 256, 0, stream>>>(hbbuf, nrange, srcs, sbuf);                   // s1 (fp32)
    lin_mfma_kernel<H1, H1, 1><<<mfmaGrid, 256, 0, stream>>>(sbuf, gc1_W, gc1_b, hbbuf, N);   // h2 (bf16)
    agg_kernel<<<(N + 3) / 4, 256, 0, stream>>>(hbbuf, nrange, srcs, sbuf);                   // s2 (fp32)
    lin_mfma_kernel<H1, H2, 2><<<mfmaGrid, 256, 0, stream>>>(sbuf, gc2_W, gc2_b, hn_out, N);  // normalized h

    // fused Set2Set (all 4 steps, one block per graph, LDS node cache)
    set2set_kernel<<<NG, 256, 0, stream>>>(hn_out, gstart,
                                           l0_Wih, l0_Whh, l0_bih, l0_bhh,
                                           l1_Wih, l1_Whh, l1_bih, l1_bhh, qstar);

    // head
    fcout_kernel<<<2, 256, 0, stream>>>(qstar, fc1_W, fc1_b, fc2_W, fc2_b, out);
}

// Round 7
// 469.932 us; speedup vs baseline: 3.0750x; 1.0847x over previous
//
#include <hip/hip_runtime.h>
#include <hip/hip_bf16.h>
#include <math.h>

// Problem constants (fixed by the reference).
constexpr int N  = 100000;   // nodes
constexpr int E  = 1600000;  // edges
constexpr int NG = 512;      // graphs
constexpr int NF = 64;
constexpr int H1 = 128;
constexpr int H2 = 64;

// CSR bucket binning
constexpr int BW   = 256;                 // nodes per bucket (dst >> 8)
constexpr int NB   = (N + BW - 1) / BW;   // 391 buckets
constexpr int CAP  = 4864;                // per-bucket edge capacity (mean 4096 + 12 sigma)
constexpr int CHUNK = 8192;               // edges per bin_scatter block

// Set2Set LDS node cache
constexpr int MAXN = 416;                 // mean 195 + 15.8 sigma; global fallback beyond
constexpr int RST  = 68;                  // row stride in ushorts

typedef __attribute__((ext_vector_type(8))) short short8;
typedef __attribute__((ext_vector_type(4))) float f32x4;

__device__ __forceinline__ float gelu_f(float x) {
    return 0.5f * x * (1.0f + erff(x * 0.70710678118654752f));
}
__device__ __forceinline__ float sigmoid_f(float x) {
    return 1.0f / (1.0f + expf(-x));
}
__device__ __forceinline__ float waveAllSum(float v) {
    #pragma unroll
    for (int m = 32; m; m >>= 1) v += __shfl_xor(v, m);
    return v;
}
__device__ __forceinline__ unsigned short f2bf(float x) {
    __hip_bfloat16 b = __float2bfloat16(x);
    return *reinterpret_cast<unsigned short*>(&b);
}
__device__ __forceinline__ float bf2f(unsigned short u) {
    return __uint_as_float(((unsigned int)u) << 16);
}
__device__ __forceinline__ float bf_lo(unsigned int u) { return __uint_as_float(u << 16); }
__device__ __forceinline__ float bf_hi(unsigned int u) { return __uint_as_float(u & 0xffff0000u); }

// split v into bf16 hi + bf16 lo (v ~= hi + lo)
__device__ __forceinline__ void bfsplit(float v, unsigned short& hi, unsigned short& lo) {
    hi = f2bf(v);
    lo = f2bf(v - bf2f(hi));
}

// ---------------- CSR build, phase 0: init bucket cursors ----------------
__global__ __launch_bounds__(256) void bcur_init_kernel(int* __restrict__ bcursor) {
    int b = blockIdx.x * 256 + threadIdx.x;
    if (b < NB) bcursor[b] = b * CAP;
}

// ---------------- CSR build, phase 1: bin edges into bucket-strided (src,dst) pairs ----
__global__ __launch_bounds__(256) void bin_scatter_kernel(const int* __restrict__ ei,
                                                          int* __restrict__ bcursor,
                                                          int2* __restrict__ pairs) {
    __shared__ int hist[NB];
    __shared__ int start_s[NB];
    __shared__ int lcur[NB];
    int tid = threadIdx.x;
    int e0 = blockIdx.x * CHUNK;
    for (int b = tid; b < NB; b += 256) hist[b] = 0;
    __syncthreads();
    #pragma unroll 4
    for (int k = 0; k < CHUNK / 256; ++k) {
        int e = e0 + k * 256 + tid;
        if (e < E) atomicAdd(&hist[ei[E + e] >> 8], 1);
    }
    __syncthreads();
    for (int b = tid; b < NB; b += 256) {
        if (hist[b]) start_s[b] = atomicAdd(&bcursor[b], hist[b]);
        lcur[b] = 0;
    }
    __syncthreads();
    #pragma unroll 4
    for (int k = 0; k < CHUNK / 256; ++k) {
        int e = e0 + k * 256 + tid;
        if (e < E) {
            int d = ei[E + e];
            int s = ei[e];
            int b = d >> 8;
            int pos = start_s[b] + atomicAdd(&lcur[b], 1);
            if (pos < (b + 1) * CAP) pairs[pos] = make_int2(s, d);
        }
    }
}

// ---------------- CSR build, phase 2: per-bucket local CSR in LDS ----------------
__global__ __launch_bounds__(256) void csr_bucket_kernel(const int2* __restrict__ pairs,
                                                         const int* __restrict__ bcursor,
                                                         int* __restrict__ srcs,
                                                         int2* __restrict__ nrange) {
    __shared__ int cnt_l[256];
    __shared__ int cur_l[256];
    __shared__ int wt[4];
    int b = blockIdx.x;
    int tid = threadIdx.x;
    int base = b * CAP;
    int cnt = bcursor[b] - base;
    if (cnt > CAP) cnt = CAP;
    cnt_l[tid] = 0;
    __syncthreads();
    for (int i = tid; i < cnt; i += 256) {
        atomicAdd(&cnt_l[pairs[base + i].y & 255], 1);
    }
    __syncthreads();
    int v = cnt_l[tid];
    int lane = tid & 63, w = tid >> 6;
    int incl = v;
    #pragma unroll
    for (int off = 1; off < 64; off <<= 1) {
        int t = __shfl_up(incl, off);
        if (lane >= off) incl += t;
    }
    if (lane == 63) wt[w] = incl;
    __syncthreads();
    int add = 0;
    for (int i = 0; i < w; ++i) add += wt[i];
    int excl = add + incl - v;
    int node = b * 256 + tid;
    if (node < N) {
        nrange[node] = make_int2(base + excl, base + excl + v);
    }
    cur_l[tid] = excl;
    __syncthreads();
    for (int i = tid; i < cnt; i += 256) {
        int2 p = pairs[base + i];
        int d = p.y & 255;
        int pos = atomicAdd(&cur_l[d], 1);
        srcs[base + pos] = p.x;
    }
}

// ---------------- graph ranges via binary search (batch is sorted) ----------------
__global__ __launch_bounds__(256) void gstart_kernel(const int* __restrict__ batch, int* __restrict__ gstart) {
    int g = blockIdx.x * 256 + threadIdx.x;
    if (g > NG) return;
    if (g == NG) { gstart[NG] = N; return; }
    int lo = 0, hi = N;
    while (lo < hi) {
        int mid = (lo + hi) >> 1;
        if (batch[mid] < g) lo = mid + 1; else hi = mid;
    }
    gstart[g] = lo;
}

// ---------------- LSTM weight transpose (one-time): WT[k][j] = W[j][k], fused biases ----
__global__ __launch_bounds__(256) void wt_kernel(const float* __restrict__ Wih0, const float* __restrict__ Whh0,
                                                 const float* __restrict__ bih0, const float* __restrict__ bhh0,
                                                 const float* __restrict__ Wih1, const float* __restrict__ Whh1,
                                                 const float* __restrict__ bih1, const float* __restrict__ bhh1,
                                                 float* __restrict__ WT0, float* __restrict__ WT1,
                                                 float* __restrict__ b0, float* __restrict__ b1) {
    int i = blockIdx.x * 256 + threadIdx.x;
    if (i < 192 * 256) {
        int k = i >> 8, j = i & 255;
        WT0[i] = (k < 128) ? Wih0[j * 128 + k] : Whh0[j * 64 + (k - 128)];
    }
    if (i < 128 * 256) {
        int k = i >> 8, j = i & 255;
        WT1[i] = (k < 64) ? Wih1[j * 64 + k] : Whh1[j * 64 + (k - 64)];
    }
    if (i < 256) { b0[i] = bih0[i] + bhh0[i]; b1[i] = bih1[i] + bhh1[i]; }
}

// ---------------- MFMA bf16x3 linear: out = act(in @ W.T + b) ----------------
template <int ID, int OD, int OUT_MODE>
__global__ __launch_bounds__(256) void lin_mfma_kernel(const float* __restrict__ in,
                                                       const float* __restrict__ W,
                                                       const float* __restrict__ bias,
                                                       void* __restrict__ out_v, int nrows) {
    constexpr int KC = 32;
    constexpr int NCH = ID / KC;
    constexpr int AST = 40;
    constexpr int NCT = OD / 16;
    constexpr int LDSU = 2 * 128 * AST + 2 * OD * AST;
    __shared__ __align__(16) unsigned short lds[LDSU];
    unsigned short* Ahi = lds;
    unsigned short* Alo = lds + 128 * AST;
    unsigned short* Whi = lds + 2 * 128 * AST;
    unsigned short* Wlo = lds + 2 * 128 * AST + OD * AST;

    int tid = threadIdx.x;
    int w = tid >> 6, lane = tid & 63;
    int m15 = lane & 15, quad = lane >> 4;
    int nb = blockIdx.x * 128;

    f32x4 acc[2][NCT];
    #pragma unroll
    for (int rt = 0; rt < 2; ++rt)
        #pragma unroll
        for (int ct = 0; ct < NCT; ++ct) acc[rt][ct] = (f32x4)0.f;

    for (int c = 0; c < NCH; ++c) {
        int kb = c * KC;
        #pragma unroll
        for (int it = 0; it < 4; ++it) {
            int f4 = it * 256 + tid;
            int row = f4 >> 3, kq = (f4 & 7) * 4;
            float4 v = make_float4(0.f, 0.f, 0.f, 0.f);
            if (nb + row < nrows) v = *(const float4*)&in[(size_t)(nb + row) * ID + kb + kq];
            unsigned short h0, h1, h2, h3, l0, l1, l2, l3;
            bfsplit(v.x, h0, l0); bfsplit(v.y, h1, l1);
            bfsplit(v.z, h2, l2); bfsplit(v.w, h3, l3);
            uint2 uh, ul;
            uh.x = (unsigned int)h0 | ((unsigned int)h1 << 16);
            uh.y = (unsigned int)h2 | ((unsigned int)h3 << 16);
            ul.x = (unsigned int)l0 | ((unsigned int)l1 << 16);
            ul.y = (unsigned int)l2 | ((unsigned int)l3 << 16);
            *(uint2*)&Ahi[row * AST + kq] = uh;
            *(uint2*)&Alo[row * AST + kq] = ul;
        }
        #pragma unroll
        for (int it = 0; it < OD / 32; ++it) {
            int f4 = it * 256 + tid;
            int o = f4 >> 3, kq = (f4 & 7) * 4;
            float4 v = *(const float4*)&W[(size_t)o * ID + kb + kq];
            unsigned short h0, h1, h2, h3, l0, l1, l2, l3;
            bfsplit(v.x, h0, l0); bfsplit(v.y, h1, l1);
            bfsplit(v.z, h2, l2); bfsplit(v.w, h3, l3);
            uint2 uh, ul;
            uh.x = (unsigned int)h0 | ((unsigned int)h1 << 16);
            uh.y = (unsigned int)h2 | ((unsigned int)h3 << 16);
            ul.x = (unsigned int)l0 | ((unsigned int)l1 << 16);
            ul.y = (unsigned int)l2 | ((unsigned int)l3 << 16);
            *(uint2*)&Whi[o * AST + kq] = uh;
            *(uint2*)&Wlo[o * AST + kq] = ul;
        }
        __syncthreads();

        short8 ah0 = *(const short8*)&Ahi[(w * 32 + m15) * AST + quad * 8];
        short8 ah1 = *(const short8*)&Ahi[(w * 32 + 16 + m15) * AST + quad * 8];
        short8 al0 = *(const short8*)&Alo[(w * 32 + m15) * AST + quad * 8];
        short8 al1 = *(const short8*)&Alo[(w * 32 + 16 + m15) * AST + quad * 8];
        #pragma unroll
        for (int ct = 0; ct < NCT; ++ct) {
            short8 bh = *(const short8*)&Whi[(ct * 16 + m15) * AST + quad * 8];
            short8 bl = *(const short8*)&Wlo[(ct * 16 + m15) * AST + quad * 8];
            acc[0][ct] = __builtin_amdgcn_mfma_f32_16x16x32_bf16(ah0, bh, acc[0][ct], 0, 0, 0);
            acc[0][ct] = __builtin_amdgcn_mfma_f32_16x16x32_bf16(ah0, bl, acc[0][ct], 0, 0, 0);
            acc[0][ct] = __builtin_amdgcn_mfma_f32_16x16x32_bf16(al0, bh, acc[0][ct], 0, 0, 0);
            acc[1][ct] = __builtin_amdgcn_mfma_f32_16x16x32_bf16(ah1, bh, acc[1][ct], 0, 0, 0);
            acc[1][ct] = __builtin_amdgcn_mfma_f32_16x16x32_bf16(ah1, bl, acc[1][ct], 0, 0, 0);
            acc[1][ct] = __builtin_amdgcn_mfma_f32_16x16x32_bf16(al1, bh, acc[1][ct], 0, 0, 0);
        }
        __syncthreads();
    }

    float bcol[NCT];
    #pragma unroll
    for (int ct = 0; ct < NCT; ++ct) bcol[ct] = bias[ct * 16 + m15];

    if (OUT_MODE == 1) {
        constexpr int EPS = OD + 8;
        unsigned short* ep = lds;
        #pragma unroll
        for (int rt = 0; rt < 2; ++rt)
            #pragma unroll
            for (int ct = 0; ct < NCT; ++ct)
                #pragma unroll
                for (int r = 0; r < 4; ++r) {
                    int rl = w * 32 + rt * 16 + quad * 4 + r;
                    float v = gelu_f(acc[rt][ct][r] + bcol[ct]);
                    ep[rl * EPS + ct * 16 + m15] = f2bf(v);
                }
        __syncthreads();
        constexpr int U4 = 128 * OD / 8;
        for (int i = tid; i < U4; i += 256) {
            int row = i / (OD / 8);
            int off = (i % (OD / 8)) * 8;
            int grow = nb + row;
            if (grow < nrows) {
                uint4 v = *(const uint4*)&ep[row * EPS + off];
                *(uint4*)((unsigned short*)out_v + (size_t)grow * OD + off) = v;
            }
        }
    } else {
        float* out = (float*)out_v;
        #pragma unroll
        for (int rt = 0; rt < 2; ++rt) {
            #pragma unroll
            for (int r = 0; r < 4; ++r) {
                float vv[NCT];
                float ss = 0.f;
                #pragma unroll
                for (int ct = 0; ct < NCT; ++ct) {
                    vv[ct] = gelu_f(acc[rt][ct][r] + bcol[ct]);
                    ss += vv[ct] * vv[ct];
                }
                #pragma unroll
                for (int mm = 1; mm < 16; mm <<= 1) ss += __shfl_xor(ss, mm);
                float denom = fmaxf(sqrtf(ss), 1e-12f);
                int grow = nb + w * 32 + rt * 16 + quad * 4 + r;
                if (grow < nrows) {
                    #pragma unroll
                    for (int ct = 0; ct < NCT; ++ct)
                        out[(size_t)grow * OD + ct * 16 + m15] = vv[ct] / denom;
                }
            }
        }
    }
}

// ---------------- GIN aggregation (bf16 table, half-wave uint2 gather) ----------------
// wave per node; lanes 0-31 handle even edges, 32-63 odd; lane reads uint2 = feats 4hl..4hl+3
__global__ __launch_bounds__(256) void agg_kernel(const uint2* __restrict__ hb2,
                                                  const int2* __restrict__ nrange,
                                                  const int* __restrict__ srcs,
                                                  float4* __restrict__ out4) {
    int wave = threadIdx.x >> 6, lane = threadIdx.x & 63;
    int half = lane >> 5, hl = lane & 31;
    int n = blockIdx.x * 4 + wave;
    if (n >= N) return;
    int2 rng = nrange[n];
    int s0 = rng.x, deg = rng.y - rng.x;
    int m1 = deg < 64 ? deg : 64;
    int pre = (lane < m1) ? srcs[s0 + lane] : 0;
    float a0 = 0.f, a1 = 0.f, a2 = 0.f, a3 = 0.f;
    int t = 0;
    for (; t + 8 <= m1; t += 8) {   // 4 pairs = 8 edges, 4 independent loads
        int i0 = __shfl(pre, t + half);
        int i1 = __shfl(pre, t + 2 + half);
        int i2 = __shfl(pre, t + 4 + half);
        int i3 = __shfl(pre, t + 6 + half);
        uint2 u0 = hb2[(size_t)i0 * 32 + hl];
        uint2 u1 = hb2[(size_t)i1 * 32 + hl];
        uint2 u2 = hb2[(size_t)i2 * 32 + hl];
        uint2 u3 = hb2[(size_t)i3 * 32 + hl];
        a0 += bf_lo(u0.x); a1 += bf_hi(u0.x); a2 += bf_lo(u0.y); a3 += bf_hi(u0.y);
        a0 += bf_lo(u1.x); a1 += bf_hi(u1.x); a2 += bf_lo(u1.y); a3 += bf_hi(u1.y);
        a0 += bf_lo(u2.x); a1 += bf_hi(u2.x); a2 += bf_lo(u2.y); a3 += bf_hi(u2.y);
        a0 += bf_lo(u3.x); a1 += bf_hi(u3.x); a2 += bf_lo(u3.y); a3 += bf_hi(u3.y);
    }
    for (; t < m1; t += 2) {
        int idx = t + half;
        int idc = idx < m1 ? idx : 0;
        int s = __shfl(pre, idc);
        if (idx < m1) {
            uint2 u = hb2[(size_t)s * 32 + hl];
            a0 += bf_lo(u.x); a1 += bf_hi(u.x); a2 += bf_lo(u.y); a3 += bf_hi(u.y);
        }
    }
    for (int j = 64 + half; j < deg; j += 2) {  // statistically never
        int s = srcs[s0 + j];
        uint2 u = hb2[(size_t)s * 32 + hl];
        a0 += bf_lo(u.x); a1 += bf_hi(u.x); a2 += bf_lo(u.y); a3 += bf_hi(u.y);
    }
    a0 += __shfl_down(a0, 32);
    a1 += __shfl_down(a1, 32);
    a2 += __shfl_down(a2, 32);
    a3 += __shfl_down(a3, 32);
    if (half == 0) {
        uint2 u = hb2[(size_t)n * 32 + hl];  // self row (GIN eps=0)
        a0 += bf_lo(u.x); a1 += bf_hi(u.x); a2 += bf_lo(u.y); a3 += bf_hi(u.y);
        out4[(size_t)n * 32 + hl] = make_float4(a0, a1, a2, a3);  // row = 32 float4 (BUGFIX: was 16)
    }
}

// ---------------- fused Set2Set: one block per graph, LDS node cache, coalesced WT ----
__global__ __launch_bounds__(256) void set2set_kernel(const float* __restrict__ hn,
                                                      const int* __restrict__ gstart,
                                                      const float* __restrict__ WT0, const float* __restrict__ b0,
                                                      const float* __restrict__ WT1, const float* __restrict__ b1,
                                                      float* __restrict__ qstar_out) {
    __shared__ __align__(16) unsigned short hL[MAXN * RST];  // bf16 node rows
    __shared__ float av[MAXN];
    __shared__ __align__(16) float xc0[192];   // [q_star(128); h0(64)]
    __shared__ __align__(16) float xc1[128];   // [h0(64); h1(64)]
    __shared__ __align__(16) float gates[256];
    __shared__ float c0v[H2], c1v[H2];
    __shared__ float red[4];
    __shared__ float rp[4][H2];
    __shared__ float sp[4];

    int g = blockIdx.x;
    int tid = threadIdx.x, w = tid >> 6, lane = tid & 63;
    int s0 = gstart[g], s1 = gstart[g + 1];
    int cnt = s1 - s0;
    int cL = cnt < MAXN ? cnt : MAXN;
    const float* hq = xc1 + 64;   // q = h1

    for (int idx = tid; idx < cL * 16; idx += 256) {
        int n = idx >> 4, p4 = idx & 15;
        float4 v = *(const float4*)&hn[(size_t)(s0 + n) * 64 + p4 * 4];
        uint2 u;
        u.x = (unsigned int)f2bf(v.x) | ((unsigned int)f2bf(v.y) << 16);
        u.y = (unsigned int)f2bf(v.z) | ((unsigned int)f2bf(v.w) << 16);
        *(uint2*)&hL[n * RST + p4 * 4] = u;
    }
    if (tid < 192) xc0[tid] = 0.f;
    if (tid < 128) xc1[tid] = 0.f;
    if (tid < H2) { c0v[tid] = 0.f; c1v[tid] = 0.f; }
    float b0v = b0[tid], b1v = b1[tid];
    __syncthreads();

    for (int step = 0; step < 4; ++step) {
        // ---- cell 0: x = [q_star; h0] (xc0), coalesced WT0 columns ----
        {
            float a0 = 0.f, a1 = 0.f, a2 = 0.f, a3 = 0.f;
            #pragma unroll 8
            for (int k = 0; k < 192; k += 4) {
                a0 += xc0[k]     * WT0[(k)     * 256 + tid];
                a1 += xc0[k + 1] * WT0[(k + 1) * 256 + tid];
                a2 += xc0[k + 2] * WT0[(k + 2) * 256 + tid];
                a3 += xc0[k + 3] * WT0[(k + 3) * 256 + tid];
            }
            gates[tid] = (a0 + a1) + (a2 + a3) + b0v;
        }
        __syncthreads();
        if (tid < H2) {
            float ii = sigmoid_f(gates[tid]), ff = sigmoid_f(gates[H2 + tid]);
            float gg = tanhf(gates[2 * H2 + tid]), oo = sigmoid_f(gates[3 * H2 + tid]);
            float c = ff * c0v[tid] + ii * gg;
            float h = oo * tanhf(c);
            c0v[tid] = c; xc0[128 + tid] = h; xc1[tid] = h;
        }
        __syncthreads();
        // ---- cell 1: x = [h0; h1] (xc1), coalesced WT1 columns ----
        {
            float a0 = 0.f, a1 = 0.f, a2 = 0.f, a3 = 0.f;
            #pragma unroll 8
            for (int k = 0; k < 128; k += 4) {
                a0 += xc1[k]     * WT1[(k)     * 256 + tid];
                a1 += xc1[k + 1] * WT1[(k + 1) * 256 + tid];
                a2 += xc1[k + 2] * WT1[(k + 2) * 256 + tid];
                a3 += xc1[k + 3] * WT1[(k + 3) * 256 + tid];
            }
            gates[tid] = (a0 + a1) + (a2 + a3) + b1v;
        }
        __syncthreads();
        if (tid < H2) {
            float ii = sigmoid_f(gates[tid]), ff = sigmoid_f(gates[H2 + tid]);
            float gg = tanhf(gates[2 * H2 + tid]), oo = sigmoid_f(gates[3 * H2 + tid]);
            float c = ff * c1v[tid] + ii * gg;
            float h = oo * tanhf(c);
            c1v[tid] = c; xc1[64 + tid] = h;   // h1 == q
        }
        __syncthreads();

        // ---- attention e-phase: one thread per node, dot from LDS ----
        float lm = -INFINITY;
        for (int i = tid; i < cnt; i += 256) {
            float e = 0.f;
            if (i < MAXN) {
                const uint2* row = (const uint2*)&hL[i * RST];
                #pragma unroll
                for (int p4 = 0; p4 < 16; ++p4) {
                    uint2 u = row[p4];
                    e += bf_lo(u.x) * hq[p4 * 4 + 0];
                    e += bf_hi(u.x) * hq[p4 * 4 + 1];
                    e += bf_lo(u.y) * hq[p4 * 4 + 2];
                    e += bf_hi(u.y) * hq[p4 * 4 + 3];
                }
                av[i] = e;
            } else {
                for (int f = 0; f < 64; ++f) e += hn[(size_t)(s0 + i) * 64 + f] * hq[f];
            }
            lm = fmaxf(lm, e);
        }
        #pragma unroll
        for (int mm = 32; mm; mm >>= 1) lm = fmaxf(lm, __shfl_xor(lm, mm));
        if (lane == 0) red[w] = lm;
        __syncthreads();
        float m = fmaxf(fmaxf(red[0], red[1]), fmaxf(red[2], red[3]));

        float ps = 0.f;
        for (int i = tid; i < cnt; i += 256) {
            float e;
            if (i < MAXN) e = av[i];
            else {
                e = 0.f;
                for (int f = 0; f < 64; ++f) e += hn[(size_t)(s0 + i) * 64 + f] * hq[f];
            }
            float p = expf(e - m);
            ps += p;
            if (i < MAXN) av[i] = p;
        }
        ps = waveAllSum(ps);
        if (lane == 0) sp[w] = ps;
        __syncthreads();
        float s = sp[0] + sp[1] + sp[2] + sp[3];

        float racc = 0.f;
        for (int i = w; i < cL; i += 4) {
            unsigned short hv = hL[i * RST + lane];
            racc += av[i] * bf2f(hv);
        }
        float qf = hq[lane];
        for (int n = MAXN + w; n < cnt; n += 4) {
            float v = hn[(size_t)(s0 + n) * 64 + lane];
            float e = waveAllSum(v * qf);
            float p = expf(e - m);
            racc += p * v;
        }
        rp[w][lane] = racc;
        __syncthreads();
        if (tid < H2) {
            float r = 0.f;
            if (cnt > 0) {
                r = (rp[0][tid] + rp[1][tid] + rp[2][tid] + rp[3][tid]) / (s + 1e-16f);
            }
            xc0[tid] = xc1[64 + tid];  // q
            xc0[H2 + tid] = r;         // r
        }
        __syncthreads();
    }
    if (tid < 2 * H2) qstar_out[g * 2 * H2 + tid] = xc0[tid];
}

// ---------------- output head: z = fc2(gelu(fc1(q_star))) ----------------
__global__ __launch_bounds__(256) void fcout_kernel(const float* __restrict__ q_star,
                                                    const float* __restrict__ W1, const float* __restrict__ b1,
                                                    const float* __restrict__ W2, const float* __restrict__ b2,
                                                    float* __restrict__ z) {
    __shared__ float W1l[32 * 128];
    __shared__ float b1l[32], W2l[32];
    int tid = threadIdx.x;
    for (int i = tid; i < 32 * 128; i += 256) W1l[i] = W1[i];
    if (tid < 32) { b1l[tid] = b1[tid]; W2l[tid] = W2[tid]; }
    __syncthreads();
    int g = blockIdx.x * 256 + tid;
    float acc[32];
    #pragma unroll
    for (int j = 0; j < 32; ++j) acc[j] = b1l[j];
    for (int k = 0; k < 128; ++k) {
        float qv = q_star[g * 128 + k];
        #pragma unroll
        for (int j = 0; j < 32; ++j) acc[j] += qv * W1l[j * 128 + k];
    }
    float zv = b2[0];
    #pragma unroll
    for (int j = 0; j < 32; ++j) zv += gelu_f(acc[j]) * W2l[j];
    z[g] = zv;
}

extern "C" void kernel_launch(void* const* d_in, const int* in_sizes, int n_in,
                              void* d_out, int out_size, void* d_ws, size_t ws_size,
                              hipStream_t stream) {
    const float* x       = (const float*)d_in[0];
    const int*   ei      = (const int*)d_in[1];
    const int*   batch   = (const int*)d_in[2];
    const float* nfc_W   = (const float*)d_in[3];
    const float* nfc_b   = (const float*)d_in[4];
    const float* gc1_W   = (const float*)d_in[5];
    const float* gc1_b   = (const float*)d_in[6];
    const float* gc2_W   = (const float*)d_in[7];
    const float* gc2_b   = (const float*)d_in[8];
    const float* l0_Wih  = (const float*)d_in[9];
    const float* l0_Whh  = (const float*)d_in[10];
    const float* l0_bih  = (const float*)d_in[11];
    const float* l0_bhh  = (const float*)d_in[12];
    const float* l1_Wih  = (const float*)d_in[13];
    const float* l1_Whh  = (const float*)d_in[14];
    const float* l1_bih  = (const float*)d_in[15];
    const float* l1_bhh  = (const float*)d_in[16];
    const float* fc1_W   = (const float*)d_in[17];
    const float* fc1_b   = (const float*)d_in[18];
    const float* fc2_W   = (const float*)d_in[19];
    const float* fc2_b   = (const float*)d_in[20];

    float* out = (float*)d_out;          // [0,512): z ; [512, 512+N*64): normalized h
    float* hn_out = out + NG;

    char* p = (char*)d_ws;
    auto take = [&](size_t bytes) {
        char* r = p;
        p += (bytes + 255) & ~size_t(255);
        return r;
    };
    float*        sbuf  = (float*)take((size_t)N * H1 * 4);        // s1 / s2 (fp32); aliased as pairs pre-lin
    unsigned int* hbbuf = (unsigned int*)take((size_t)N * H1 * 2); // h1 / h2 (bf16-packed)
    int*   srcs   = (int*)take((size_t)NB * CAP * 4);
    int2*  nrange = (int2*)take((size_t)N * 8);
    int*   bcursor= (int*)take((size_t)NB * 4);
    int*   gstart = (int*)take((size_t)(NG + 1) * 4);
    float* qstar  = (float*)take((size_t)NG * 2 * H2 * 4);
    float* WT0    = (float*)take((size_t)192 * 256 * 4);
    float* WT1    = (float*)take((size_t)128 * 256 * 4);
    float* b0     = (float*)take((size_t)256 * 4);
    float* b1     = (float*)take((size_t)256 * 4);

    int2* pairs = (int2*)sbuf;  // NB*CAP*8 = 15.2 MB, free until agg1 writes s1

    // CSR build (bucket-binned)
    bcur_init_kernel<<<(NB + 255) / 256, 256, 0, stream>>>(bcursor);
    bin_scatter_kernel<<<(E + CHUNK - 1) / CHUNK, 256, 0, stream>>>(ei, bcursor, pairs);
    csr_bucket_kernel<<<NB, 256, 0, stream>>>(pairs, bcursor, srcs, nrange);

    // graph ranges + LSTM weight transpose
    gstart_kernel<<<3, 256, 0, stream>>>(batch, gstart);
    wt_kernel<<<192, 256, 0, stream>>>(l0_Wih, l0_Whh, l0_bih, l0_bhh,
                                       l1_Wih, l1_Whh, l1_bih, l1_bhh, WT0, WT1, b0, b1);

    // node feature pipeline (MFMA bf16x3 linears)
    int mfmaGrid = (N + 127) / 128;
    lin_mfma_kernel<NF, H1, 1><<<mfmaGrid, 256, 0, stream>>>(x, nfc_W, nfc_b, hbbuf, N);      // h1 (bf16)
    agg_kernel<<<(N + 3) / 4, 256, 0, stream>>>((const uint2*)hbbuf, nrange, srcs, (float4*)sbuf);
    lin_mfma_kernel<H1, H1, 1><<<mfmaGrid, 256, 0, stream>>>(sbuf, gc1_W, gc1_b, hbbuf, N);   // h2 (bf16)
    agg_kernel<<<(N + 3) / 4, 256, 0, stream>>>((const uint2*)hbbuf, nrange, srcs, (float4*)sbuf);
    lin_mfma_kernel<H1, H2, 2><<<mfmaGrid, 256, 0, stream>>>(sbuf, gc2_W, gc2_b, hn_out, N);  // normalized h

    // fused Set2Set (all 4 steps, one block per graph, LDS node cache, coalesced WT)
    set2set_kernel<<<NG, 256, 0, stream>>>(hn_out, gstart, WT0, b0, WT1, b1, qstar);

    // head
    fcout_kernel<<<2, 256, 0, stream>>>(qstar, fc1_W, fc1_b, fc2_W, fc2_b, out);
}